// Round 2
// baseline (789.744 us; speedup 1.0000x reference)
//
#include <hip/hip_runtime.h>
#include <hip/hip_bf16.h>

typedef __hip_bfloat16 bf16;
typedef __attribute__((ext_vector_type(8))) short short8;
typedef __attribute__((ext_vector_type(4))) float f32x4;

#define DEV static __device__ __forceinline__

DEV float b2f(bf16 v) { return __bfloat162float(v); }
DEV bf16 f2b(float v) { return __float2bfloat16(v); }
DEV unsigned short f2bu(float v) { return __builtin_bit_cast(unsigned short, __float2bfloat16(v)); }
DEV float u2f(unsigned short u) { return __uint_as_float(((unsigned int)u) << 16); }
DEV float gelu(float x) { return 0.5f * x * (1.0f + erff(x * 0.70710678118654752f)); }

// Problem constants
#define BB 64
#define NT 139     // 1 + T + G1
#define DD 384
#define TT 10
#define HH 6
#define GG 138     // G1 + T
#define M1 8896    // BB*NT = 64*139, multiple of 64
#define MG 8832    // BB*GG = 64*138, multiple of 64
#define NGRP 2048  // BB*S
#define SCALE 0.125f

// Workspace byte offsets (proven layout; + bf16 weights block = 90.4 MB)
#define XC_OFF   0UL          // f32 8896x384 residual stream, live whole call
#define VIS_OFF  13664256UL   // f32 2048x384
#define XNB_OFF  16809984UL   // bf16 8896x384: LN out; attn1 o; dead after consumer
#define XFN_OFF  23642112UL   // f32 8896x384: fc2 out; x_prop
#define T16_OFF  37306368UL   // f32 8896x16
#define BIG1_OFF 37875712UL   // bf16 8896x1152: qkv / qkv1
#define BIG2_OFF 58372096UL   // bf16 8896x1536 fc1h / bf16 32768x384 o1 / f32 x_final
#define ATT_OFF  XNB_OFF      // bf16 32768x384 proj1 out (overlays dead XNB..BIG1 prefix)
#define WB_OFF   85700608UL   // bf16 2359296: pre-converted weights

// bf16 weight block element offsets
#define WB_QKV   0
#define WB_PROJ  442368
#define WB_FC1   589824
#define WB_FC2   1179648
#define WB_QKV1  1769472
#define WB_PROJ1 2211840
#define WB_TOTAL 2359296

#define OUT_X 3170304  // 64*129*384

DEV float4 ld4(const float* p) { return *(const float4*)p; }
DEV float4 ld4(const bf16* p) {
    ushort4 u = *(const ushort4*)p;
    return make_float4(u2f(u.x), u2f(u.y), u2f(u.z), u2f(u.w));
}
DEV void stc(float* p, float v) { *p = v; }
DEV void stc(bf16* p, float v) { *p = f2b(v); }

// ---------- weights f32 -> bf16 (once per call) ----------
__global__ __launch_bounds__(256) void k_wconv(const float* __restrict__ w0, const float* __restrict__ w1,
                                               const float* __restrict__ w2, const float* __restrict__ w3,
                                               const float* __restrict__ w4, const float* __restrict__ w5,
                                               bf16* __restrict__ dst) {
    int i4 = (blockIdx.x * 256 + threadIdx.x) * 4;
    if (i4 >= WB_TOTAL) return;
    const float* s; int off;
    if (i4 < WB_PROJ)       { s = w0; off = WB_QKV; }
    else if (i4 < WB_FC1)   { s = w1; off = WB_PROJ; }
    else if (i4 < WB_FC2)   { s = w2; off = WB_FC1; }
    else if (i4 < WB_QKV1)  { s = w3; off = WB_FC2; }
    else if (i4 < WB_PROJ1) { s = w4; off = WB_QKV1; }
    else                    { s = w5; off = WB_PROJ1; }
    float4 v = *(const float4*)(s + (i4 - off));
    ushort4 u;
    u.x = f2bu(v.x); u.y = f2bu(v.y); u.z = f2bu(v.z); u.w = f2bu(v.w);
    *(ushort4*)((unsigned short*)dst + i4) = u;
}

// ---------- concat: xc = [x[:, :1], prompt, x[:, 1:]] ----------
__global__ __launch_bounds__(256) void k_build_xc(const float* __restrict__ x,
                                                  const float* __restrict__ pe,
                                                  float* __restrict__ xc) {
    int i = blockIdx.x * 256 + threadIdx.x;
    if (i >= M1 * DD) return;
    int d = i % DD, r = i / DD, n = r % NT, b = r / NT;
    float v;
    if (n == 0)        v = x[(b * 129) * DD + d];
    else if (n <= TT)  v = pe[(n - 1) * DD + d];
    else               v = x[(b * 129 + n - TT) * DD + d];
    xc[i] = v;
}

// ---------- layernorm f32 -> bf16 (mode 1: gather row (r/138)*139+1+(r%138)) ----------
__global__ __launch_bounds__(128) void k_layernorm(const float* __restrict__ src, bf16* __restrict__ dst,
                                                   const float* __restrict__ g, const float* __restrict__ bta,
                                                   int mode) {
    int r = blockIdx.x;
    int srow = r;
    if (mode) srow = (r / GG) * NT + 1 + (r % GG);
    const float* p = src + (size_t)srow * DD;
    int t = threadIdx.x;
    float v0 = p[t], v1 = p[t + 128], v2 = p[t + 256];
    __shared__ float red[4];
    float s = v0 + v1 + v2;
    for (int off = 32; off; off >>= 1) s += __shfl_down(s, off, 64);
    if ((t & 63) == 0) red[t >> 6] = s;
    __syncthreads();
    float mean = (red[0] + red[1]) * (1.0f / 384.0f);
    float d0 = v0 - mean, d1 = v1 - mean, d2 = v2 - mean;
    float s2 = d0 * d0 + d1 * d1 + d2 * d2;
    for (int off = 32; off; off >>= 1) s2 += __shfl_down(s2, off, 64);
    if ((t & 63) == 0) red[2 + (t >> 6)] = s2;
    __syncthreads();
    float rstd = rsqrtf((red[2] + red[3]) * (1.0f / 384.0f) + 1e-5f);
    bf16* q = dst + (size_t)r * DD;
    q[t]       = f2b(d0 * rstd * g[t]       + bta[t]);
    q[t + 128] = f2b(d1 * rstd * g[t + 128] + bta[t + 128]);
    q[t + 256] = f2b(d2 * rstd * g[t + 256] + bta[t + 256]);
}

// ---------- MFMA GEMM: C[M,N] = act(A[M,K]bf16 @ W[N,K]^T bf16 + bias) (+res)
// Block tile 64 x BN (BN = 64 or 128), BK=64, 4 waves (2x2); each wave 32 x BN/2
// via 2 x (BN/32) 16x16x32 fragments x 2 k-slices. 2-stage register prefetch
// (load tile k+1 to regs while computing tile k from LDS) — proven structure;
// BN=128 raises MFMA:ds_read from 1:1 to 16:12 and halves staging per output.
// Requires: M % 64 == 0, N % BN == 0, K % 64 == 0 (true at all call sites).
template <int BN, typename TC>
__global__ __launch_bounds__(256) void mf_gemm(const bf16* __restrict__ A, const bf16* __restrict__ W,
                                               const float* __restrict__ bias, const float* __restrict__ res,
                                               TC* __restrict__ C, int M, int N, int K, int act) {
    constexpr int NI  = BN / 32;       // n-fragments per wave (2 or 4)
    constexpr int TPR = 256 / BN;      // threads per W row (4 or 2)
    constexpr int WU4 = 64 / TPR / 8;  // uint4 per thread for W staging (2 or 4)
    __shared__ bf16 As[64][72];
    __shared__ bf16 Ws[BN][72];
    int t = threadIdx.x;
    int m0 = blockIdx.y * 64, n0 = blockIdx.x * BN;
    int lane = t & 63, wv = t >> 6;
    int wm = (wv >> 1) * 32, wn = (wv & 1) * (BN / 2);
    int fr = lane & 15, fq = lane >> 4;
    int sr = t >> 2, sc = (t & 3) * 16;            // A staging: 4 thr/row, 32B each
    int wr = t / TPR, wc = (t % TPR) * (64 / TPR); // W staging: TPR thr/row
    const bf16* pa = A + (size_t)(m0 + sr) * K + sc;
    const bf16* pw = W + (size_t)(n0 + wr) * K + wc;
    uint4 ra[2], rw[WU4];
    ra[0] = *(const uint4*)pa;
    ra[1] = *(const uint4*)(pa + 8);
#pragma unroll
    for (int i = 0; i < WU4; ++i) rw[i] = *(const uint4*)(pw + i * 8);
    f32x4 acc[2][NI] = {};
    int k0 = 0;
    for (;;) {
        *(uint4*)&As[sr][sc] = ra[0];
        *(uint4*)&As[sr][sc + 8] = ra[1];
#pragma unroll
        for (int i = 0; i < WU4; ++i) *(uint4*)&Ws[wr][wc + i * 8] = rw[i];
        __syncthreads();
        k0 += 64;
        bool more = (k0 < K);
        if (more) {
            ra[0] = *(const uint4*)(pa + k0);
            ra[1] = *(const uint4*)(pa + k0 + 8);
#pragma unroll
            for (int i = 0; i < WU4; ++i) rw[i] = *(const uint4*)(pw + k0 + i * 8);
        }
#pragma unroll
        for (int ks = 0; ks < 2; ++ks) {
            short8 a[2], b[NI];
#pragma unroll
            for (int mi = 0; mi < 2; ++mi)
                a[mi] = *(const short8*)&As[wm + mi * 16 + fr][ks * 32 + fq * 8];
#pragma unroll
            for (int ni = 0; ni < NI; ++ni)
                b[ni] = *(const short8*)&Ws[wn + ni * 16 + fr][ks * 32 + fq * 8];
#pragma unroll
            for (int mi = 0; mi < 2; ++mi)
#pragma unroll
                for (int ni = 0; ni < NI; ++ni)
                    acc[mi][ni] = __builtin_amdgcn_mfma_f32_16x16x32_bf16(a[mi], b[ni], acc[mi][ni], 0, 0, 0);
        }
        if (!more) break;
        __syncthreads();
    }
#pragma unroll
    for (int mi = 0; mi < 2; ++mi) {
#pragma unroll
        for (int r = 0; r < 4; ++r) {
            int row = m0 + wm + mi * 16 + fq * 4 + r;
            size_t ro = (size_t)row * N;
#pragma unroll
            for (int ni = 0; ni < NI; ++ni) {
                int col = n0 + wn + ni * 16 + fr;
                float c = acc[mi][ni][r];
                if (bias) c += bias[col];
                if (act == 1) c = gelu(c);
                if (res) c += res[ro + col];
                stc(&C[ro + col], c);
            }
        }
    }
}

// ---------- small fp32 GEMM (N=16 adapters) ----------
#define BM 64
#define BNN 64
#define BKK 16
template <typename TA, typename TC>
__global__ __launch_bounds__(256) void k_gemm(const TA* __restrict__ A, const float* __restrict__ W,
                                              const float* __restrict__ bias, const float* __restrict__ res,
                                              TC* __restrict__ C, int M, int N, int K, int act) {
    __shared__ float As[BKK][BM + 4];
    __shared__ float Wsm[BKK][BNN + 4];
    int t = threadIdx.x;
    int tx = t & 15, ty = t >> 4;
    int m0 = blockIdx.y * BM, n0 = blockIdx.x * BNN;
    int lr = t >> 2;
    int lk = (t & 3) * 4;
    float acc[4][4] = {};
    for (int k0 = 0; k0 < K; k0 += BKK) {
        float4 av = ld4(A + (size_t)(m0 + lr) * K + k0 + lk);
        As[lk + 0][lr] = av.x; As[lk + 1][lr] = av.y;
        As[lk + 2][lr] = av.z; As[lk + 3][lr] = av.w;
        int wrr = n0 + lr;
        float4 wv = make_float4(0.f, 0.f, 0.f, 0.f);
        if (wrr < N) wv = ld4(W + (size_t)wrr * K + k0 + lk);
        Wsm[lk + 0][lr] = wv.x; Wsm[lk + 1][lr] = wv.y;
        Wsm[lk + 2][lr] = wv.z; Wsm[lk + 3][lr] = wv.w;
        __syncthreads();
#pragma unroll
        for (int k = 0; k < BKK; ++k) {
            float a0 = As[k][ty * 4 + 0], a1 = As[k][ty * 4 + 1];
            float a2 = As[k][ty * 4 + 2], a3 = As[k][ty * 4 + 3];
            float b0 = Wsm[k][tx * 4 + 0], b1 = Wsm[k][tx * 4 + 1];
            float b2 = Wsm[k][tx * 4 + 2], b3 = Wsm[k][tx * 4 + 3];
            acc[0][0] += a0 * b0; acc[0][1] += a0 * b1; acc[0][2] += a0 * b2; acc[0][3] += a0 * b3;
            acc[1][0] += a1 * b0; acc[1][1] += a1 * b1; acc[1][2] += a1 * b2; acc[1][3] += a1 * b3;
            acc[2][0] += a2 * b0; acc[2][1] += a2 * b1; acc[2][2] += a2 * b2; acc[2][3] += a2 * b3;
            acc[3][0] += a3 * b0; acc[3][1] += a3 * b1; acc[3][2] += a3 * b2; acc[3][3] += a3 * b3;
        }
        __syncthreads();
    }
#pragma unroll
    for (int i = 0; i < 4; ++i) {
        int m = m0 + ty * 4 + i;
        size_t ro = (size_t)m * N;
#pragma unroll
        for (int j = 0; j < 4; ++j) {
            int n = n0 + tx * 4 + j;
            if (n < N) {
                float c = acc[i][j];
                if (bias) c += bias[n];
                if (act == 1) c = gelu(c);
                if (res) c += res[ro + n];
                stc(&C[ro + n], c);
            }
        }
    }
}

// ---------- stage-1 attention (MFMA): one block per (b,h) ----------
__global__ __launch_bounds__(256) void k_attn1(const bf16* __restrict__ qkv, bf16* __restrict__ o_out,
                                               float* __restrict__ attn_out) {
    int bh = blockIdx.x;
    int b = bh / HH, h = bh % HH;
    __shared__ unsigned short Kl[144][72];
    __shared__ unsigned short Vt[64][160];
    __shared__ unsigned short Pl[4][16][160];
    int t = threadIdx.x;
    int lane = t & 63, wv = t >> 6;
    int fr = lane & 15, fq = lane >> 4;
    const unsigned short* q16 = (const unsigned short*)qkv;
    size_t base = (size_t)b * NT * 1152;

    uint4 z4 = make_uint4(0, 0, 0, 0);
    for (int i = t * 8; i < 64 * 160; i += 2048) *(uint4*)(&Vt[0][0] + i) = z4;
    for (int i = t * 8; i < 4 * 16 * 160; i += 2048) *(uint4*)(&Pl[0][0][0] + i) = z4;
    for (int i = t; i < 144 * 8; i += 256) {
        int row = i >> 3, ch = (i & 7) * 8;
        uint4 v = z4;
        if (row < NT) v = *(const uint4*)(q16 + base + row * 1152 + 384 + h * 64 + ch);
        *(uint4*)&Kl[row][ch] = v;
    }
    for (int i = t; i < NT * 16; i += 256) {
        int m = i >> 4, dq = (i & 15) * 4;
        ushort4 v = *(const ushort4*)(q16 + base + m * 1152 + 768 + h * 64 + dq);
        Vt[dq + 0][m] = v.x; Vt[dq + 1][m] = v.y;
        Vt[dq + 2][m] = v.z; Vt[dq + 3][m] = v.w;
    }
    __syncthreads();

    for (int nt = wv; nt < 9; nt += 4) {
        int n0 = nt * 16;
        int arow = n0 + fr; if (arow > NT - 1) arow = NT - 1;
        const unsigned short* qp = q16 + base + (size_t)arow * 1152 + h * 64 + fq * 8;
        short8 a0 = *(const short8*)qp;
        short8 a1 = *(const short8*)(qp + 32);
        f32x4 s[9] = {};
#pragma unroll
        for (int mt = 0; mt < 9; ++mt) {
            short8 b0 = *(const short8*)&Kl[mt * 16 + fr][fq * 8];
            short8 b1 = *(const short8*)&Kl[mt * 16 + fr][32 + fq * 8];
            s[mt] = __builtin_amdgcn_mfma_f32_16x16x32_bf16(a0, b0, s[mt], 0, 0, 0);
            s[mt] = __builtin_amdgcn_mfma_f32_16x16x32_bf16(a1, b1, s[mt], 0, 0, 0);
        }
#pragma unroll
        for (int r = 0; r < 4; ++r) {
            float e[9];
            float mx = -1e30f;
#pragma unroll
            for (int mt = 0; mt < 9; ++mt) {
                int col = mt * 16 + fr;
                float v = (col < NT) ? s[mt][r] * SCALE : -1e30f;
                e[mt] = v;
                mx = fmaxf(mx, v);
            }
#pragma unroll
            for (int off = 1; off < 16; off <<= 1) mx = fmaxf(mx, __shfl_xor(mx, off, 64));
            float sm = 0.f;
#pragma unroll
            for (int mt = 0; mt < 9; ++mt) { e[mt] = __expf(e[mt] - mx); sm += e[mt]; }
#pragma unroll
            for (int off = 1; off < 16; off <<= 1) sm += __shfl_xor(sm, off, 64);
            float inv = 1.0f / sm;
            int n = n0 + fq * 4 + r;
            bool nv = n < NT;
            size_t ab = ((size_t)(b * HH + h) * NT + n) * NT;
#pragma unroll
            for (int mt = 0; mt < 9; ++mt) {
                float p = e[mt] * inv;
                int col = mt * 16 + fr;
                if (nv && col < NT) attn_out[ab + col] = p;
                Pl[wv][fq * 4 + r][col] = f2bu(p);
            }
        }
        __syncthreads();
        f32x4 oac[4] = {};
#pragma unroll
        for (int ks = 0; ks < 5; ++ks) {
            short8 ap = *(const short8*)&Pl[wv][fr][ks * 32 + fq * 8];
#pragma unroll
            for (int dt = 0; dt < 4; ++dt) {
                short8 bv = *(const short8*)&Vt[dt * 16 + fr][ks * 32 + fq * 8];
                oac[dt] = __builtin_amdgcn_mfma_f32_16x16x32_bf16(ap, bv, oac[dt], 0, 0, 0);
            }
        }
#pragma unroll
        for (int dt = 0; dt < 4; ++dt)
#pragma unroll
            for (int r = 0; r < 4; ++r) {
                int n = n0 + fq * 4 + r;
                if (n < NT)
                    o_out[((size_t)(b * NT + n)) * DD + h * 64 + dt * 16 + fr] = f2b(oac[dt][r]);
            }
    }
}

// ---------- stage-2 per-group attention (MFMA): one wave per group ----------
__global__ __launch_bounds__(64) void k_attn2(const bf16* __restrict__ qkv, const int* __restrict__ idx,
                                              bf16* __restrict__ o1) {
    int g = blockIdx.x;
    __shared__ unsigned short Vt2[64][40];
    __shared__ unsigned short P2[16][40];
    __shared__ int ridx[16];
    int t = threadIdx.x;
    int fr = t & 15, fq = t >> 4;
    const unsigned short* q16 = (const unsigned short*)qkv;
    if (t < 16) ridx[t] = idx[g * 16 + t];
    uint4 z4 = make_uint4(0, 0, 0, 0);
    for (int i = t * 8; i < 64 * 40; i += 512) *(uint4*)(&Vt2[0][0] + i) = z4;
    for (int i = t * 8; i < 16 * 40; i += 512) *(uint4*)(&P2[0][0] + i) = z4;
    __syncthreads();
    size_t qb = (size_t)ridx[fr] * 1152;
    for (int h = 0; h < HH; ++h) {
        for (int i = t; i < 256; i += 64) {
            int m = i >> 4, dq = (i & 15) * 4;
            ushort4 v = *(const ushort4*)(q16 + (size_t)ridx[m] * 1152 + 768 + h * 64 + dq);
            Vt2[dq + 0][m] = v.x; Vt2[dq + 1][m] = v.y;
            Vt2[dq + 2][m] = v.z; Vt2[dq + 3][m] = v.w;
        }
        __syncthreads();
        const unsigned short* qp = q16 + qb + h * 64 + fq * 8;
        const unsigned short* kp = q16 + qb + 384 + h * 64 + fq * 8;
        short8 a0 = *(const short8*)qp;
        short8 a1 = *(const short8*)(qp + 32);
        short8 b0 = *(const short8*)kp;
        short8 b1 = *(const short8*)(kp + 32);
        f32x4 s = {};
        s = __builtin_amdgcn_mfma_f32_16x16x32_bf16(a0, b0, s, 0, 0, 0);
        s = __builtin_amdgcn_mfma_f32_16x16x32_bf16(a1, b1, s, 0, 0, 0);
#pragma unroll
        for (int r = 0; r < 4; ++r) {
            float v = s[r] * SCALE;
            float mx = v;
#pragma unroll
            for (int off = 1; off < 16; off <<= 1) mx = fmaxf(mx, __shfl_xor(mx, off, 64));
            float e = __expf(v - mx), sm = e;
#pragma unroll
            for (int off = 1; off < 16; off <<= 1) sm += __shfl_xor(sm, off, 64);
            P2[fq * 4 + r][fr] = f2bu(e / sm);
        }
        __syncthreads();
        short8 ap = *(const short8*)&P2[fr][fq * 8];
        f32x4 oac[4] = {};
#pragma unroll
        for (int dt = 0; dt < 4; ++dt) {
            short8 bv = *(const short8*)&Vt2[dt * 16 + fr][fq * 8];
            oac[dt] = __builtin_amdgcn_mfma_f32_16x16x32_bf16(ap, bv, oac[dt], 0, 0, 0);
        }
#pragma unroll
        for (int dt = 0; dt < 4; ++dt)
#pragma unroll
            for (int r = 0; r < 4; ++r)
                o1[((size_t)(g * 16 + fq * 4 + r)) * DD + h * 64 + dt * 16 + fr] = f2b(oac[dt][r]);
        __syncthreads();
    }
}

// ---------- adapter combine: xc += 0.7*(t16 @ up^T + up_b) + xfn ----------
__global__ __launch_bounds__(128) void k_ad_combine(const float* __restrict__ t16, const float* __restrict__ upw,
                                                    const float* __restrict__ upb, const float* __restrict__ xfn,
                                                    float* xc) {
    int r = blockIdx.x, t = threadIdx.x;
    __shared__ float tl[16];
    if (t < 16) tl[t] = t16[r * 16 + t];
    __syncthreads();
    for (int d = t; d < DD; d += 128) {
        float acc = 0.f;
#pragma unroll
        for (int c = 0; c < 4; ++c) {
            float4 u = *(const float4*)(upw + d * 16 + c * 4);
            acc += tl[c * 4 + 0] * u.x + tl[c * 4 + 1] * u.y
                 + tl[c * 4 + 2] * u.z + tl[c * 4 + 3] * u.w;
        }
        acc += upb[d];
        size_t i = (size_t)r * DD + d;
        xc[i] += 0.7f * acc + xfn[i];
    }
}

// ---------- group residual + max + BN + GELU + centers -> vis ----------
__global__ __launch_bounds__(128) void k_groupmax(const bf16* __restrict__ att, const float* __restrict__ xc,
                                                  const int* __restrict__ idx, const int* __restrict__ cidx,
                                                  const float* __restrict__ bg, const float* __restrict__ bb,
                                                  const float* __restrict__ bmean, const float* __restrict__ bvar,
                                                  float* __restrict__ vis) {
    int g = blockIdx.x, t = threadIdx.x;
    __shared__ int rows[16];
    __shared__ int crow;
    if (t < 16) { int r = idx[g * 16 + t]; rows[t] = (r / GG) * NT + 1 + (r % GG); }
    if (t == 16) { int r = cidx[g]; crow = (r / GG) * NT + 1 + (r % GG); }
    __syncthreads();
    for (int d = t; d < DD; d += 128) {
        float m = -INFINITY;
#pragma unroll
        for (int j = 0; j < 16; ++j) {
            float v = b2f(att[((size_t)(g * 16 + j)) * DD + d]) + xc[(size_t)rows[j] * DD + d];
            m = fmaxf(m, v);
        }
        float bn = (m - bmean[d]) * rsqrtf(bvar[d] + 1e-5f) * bg[d] + bb[d];
        bn = gelu(bn);
        vis[(size_t)g * DD + d] = bn + 0.3f * xc[(size_t)crow * DD + d];
    }
}

// ---------- propagate ----------
__global__ __launch_bounds__(128) void k_propagate(const float* __restrict__ c1, const float* __restrict__ c2,
                                                   const float* __restrict__ xc, const float* __restrict__ vis,
                                                   float* __restrict__ xp) {
    int blk = blockIdx.x;
    int b = blk >> 7, i = blk & 127;
    int t = threadIdx.x;
    __shared__ float wl[32];
    __shared__ float wsum;
    if (t < 32) {
        float dx = c1[(b * 128 + i) * 3 + 0] - c2[(b * 32 + t) * 3 + 0];
        float dy = c1[(b * 128 + i) * 3 + 1] - c2[(b * 32 + t) * 3 + 1];
        float dz = c1[(b * 128 + i) * 3 + 2] - c2[(b * 32 + t) * 3 + 2];
        wl[t] = 1.0f / (dx * dx + dy * dy + dz * dz + 1e-8f);
    }
    __syncthreads();
    if (t == 0) {
        float s = 0.f;
        for (int j = 0; j < 32; ++j) s += wl[j];
        wsum = s;
    }
    __syncthreads();
    float sc = 0.3f / wsum;
    for (int d = t; d < DD; d += 128) {
        float acc = 0.f;
#pragma unroll 8
        for (int j = 0; j < 32; ++j) acc += wl[j] * vis[((size_t)(b * 32 + j)) * DD + d];
        xp[((size_t)(b * 128 + i)) * DD + d] = xc[((size_t)(b * NT + 11 + i)) * DD + d] + sc * acc;
    }
}

// ---------- build x_final = [cls, prompt, x_prop] ----------
__global__ __launch_bounds__(256) void k_build_xfinal(const float* __restrict__ xc, const float* __restrict__ xp,
                                                      float* __restrict__ xf) {
    int i = blockIdx.x * 256 + threadIdx.x;
    if (i >= M1 * DD) return;
    int d = i % DD, r = i / DD, n = r % NT, b = r / NT;
    xf[i] = (n < 11) ? xc[i] : xp[((size_t)(b * 128 + n - 11)) * DD + d];
}

// ---------- final adapter-up + residual + slice -> f32 out ----------
__global__ __launch_bounds__(128) void k_final(const float* __restrict__ t16, const float* __restrict__ upw,
                                               const float* __restrict__ upb, const float* __restrict__ xf,
                                               float* __restrict__ outx) {
    int rb = blockIdx.x, t = threadIdx.x;
    int b = rb / 129, no = rb % 129;
    int src = b * NT + (no == 0 ? 0 : no + TT);
    __shared__ float tl[16];
    if (t < 16) tl[t] = t16[src * 16 + t];
    __syncthreads();
    for (int d = t; d < DD; d += 128) {
        float acc = 0.f;
#pragma unroll
        for (int c = 0; c < 4; ++c) {
            float4 u = *(const float4*)(upw + d * 16 + c * 4);
            acc += tl[c * 4 + 0] * u.x + tl[c * 4 + 1] * u.y
                 + tl[c * 4 + 2] * u.z + tl[c * 4 + 3] * u.w;
        }
        acc += upb[d];
        outx[(size_t)rb * DD + d] = acc + xf[(size_t)src * DD + d];
    }
}

extern "C" void kernel_launch(void* const* d_in, const int* in_sizes, int n_in,
                              void* d_out, int out_size, void* d_ws, size_t ws_size,
                              hipStream_t stream) {
    const float* x_in    = (const float*)d_in[0];
    const float* center1 = (const float*)d_in[2];
    const float* center2 = (const float*)d_in[3];
    const int*   idx     = (const int*)d_in[5];
    const int*   cidx    = (const int*)d_in[6];
    const float* ln1_g   = (const float*)d_in[9];
    const float* ln1_b   = (const float*)d_in[10];
    const float* ln2_g   = (const float*)d_in[11];
    const float* ln2_b   = (const float*)d_in[12];
    const float* qkv_w   = (const float*)d_in[13];
    const float* proj_w  = (const float*)d_in[14];
    const float* proj_b  = (const float*)d_in[15];
    const float* fc1_w   = (const float*)d_in[16];
    const float* fc1_b   = (const float*)d_in[17];
    const float* fc2_w   = (const float*)d_in[18];
    const float* fc2_b   = (const float*)d_in[19];
    const float* ad_dw   = (const float*)d_in[20];
    const float* ad_db   = (const float*)d_in[21];
    const float* ad_uw   = (const float*)d_in[22];
    const float* ad_ub   = (const float*)d_in[23];
    const float* ad1_dw  = (const float*)d_in[24];
    const float* ad1_db  = (const float*)d_in[25];
    const float* ad1_uw  = (const float*)d_in[26];
    const float* ad1_ub  = (const float*)d_in[27];
    const float* prompt  = (const float*)d_in[28];
    const float* bn_g    = (const float*)d_in[29];
    const float* bn_b    = (const float*)d_in[30];
    const float* bn_mean = (const float*)d_in[31];
    const float* bn_var  = (const float*)d_in[32];
    const float* qkv1_w  = (const float*)d_in[33];
    const float* proj1_w = (const float*)d_in[34];
    const float* proj1_b = (const float*)d_in[35];
    const float* ln3_g   = (const float*)d_in[36];
    const float* ln3_b   = (const float*)d_in[37];

    char* wsb = (char*)d_ws;
    float* XC   = (float*)(wsb + XC_OFF);
    float* VIS  = (float*)(wsb + VIS_OFF);
    bf16*  XNB  = (bf16*)(wsb + XNB_OFF);
    float* XFN  = (float*)(wsb + XFN_OFF);
    float* T16  = (float*)(wsb + T16_OFF);
    bf16*  BIG1 = (bf16*)(wsb + BIG1_OFF);
    bf16*  BIG2 = (bf16*)(wsb + BIG2_OFF);
    float* XFIN = (float*)(wsb + BIG2_OFF);
    bf16*  ATT  = (bf16*)(wsb + ATT_OFF);
    bf16*  WB   = (bf16*)(wsb + WB_OFF);

    float* out_x    = (float*)d_out;
    float* out_attn = out_x + OUT_X;

    // --- weights -> bf16 (graph-safe: every call) ---
    k_wconv<<<(WB_TOTAL / 4 + 255) / 256, 256, 0, stream>>>(qkv_w, proj_w, fc1_w, fc2_w, qkv1_w, proj1_w, WB);

    // --- stage 1 ---
    k_build_xc<<<(M1 * DD + 255) / 256, 256, 0, stream>>>(x_in, prompt, XC);
    k_layernorm<<<M1, 128, 0, stream>>>(XC, XNB, ln1_g, ln1_b, 0);
    mf_gemm<128><<<dim3(9, 139), 256, 0, stream>>>(XNB, WB + WB_QKV, (const float*)nullptr, (const float*)nullptr, BIG1, M1, 1152, 384, 0);
    k_attn1<<<BB * HH, 256, 0, stream>>>(BIG1, XNB, out_attn);
    mf_gemm<64><<<dim3(6, 139), 256, 0, stream>>>(XNB, WB + WB_PROJ, proj_b, XC, XC, M1, 384, 384, 0);
    k_layernorm<<<M1, 128, 0, stream>>>(XC, XNB, ln2_g, ln2_b, 0);
    mf_gemm<128><<<dim3(12, 139), 256, 0, stream>>>(XNB, WB + WB_FC1, fc1_b, (const float*)nullptr, BIG2, M1, 1536, 384, 1);
    mf_gemm<64><<<dim3(6, 139), 256, 0, stream>>>(BIG2, WB + WB_FC2, fc2_b, (const float*)nullptr, XFN, M1, 384, 1536, 0);
    k_gemm<<<dim3(1, 139), 256, 0, stream>>>(XFN, ad_dw, ad_db, (const float*)nullptr, T16, M1, 16, 384, 1);
    k_ad_combine<<<M1, 128, 0, stream>>>(T16, ad_uw, ad_ub, XFN, XC);

    // --- stage 2 (group attention on 8832 unique rows) ---
    k_layernorm<<<MG, 128, 0, stream>>>(XC, XNB, ln3_g, ln3_b, 1);
    mf_gemm<128><<<dim3(9, 138), 256, 0, stream>>>(XNB, WB + WB_QKV1, (const float*)nullptr, (const float*)nullptr, BIG1, MG, 1152, 384, 0);
    k_attn2<<<NGRP, 64, 0, stream>>>(BIG1, idx, BIG2);
    mf_gemm<128><<<dim3(3, 512), 256, 0, stream>>>(BIG2, WB + WB_PROJ1, proj1_b, (const float*)nullptr, ATT, NGRP * 16, 384, 384, 0);
    k_groupmax<<<NGRP, 128, 0, stream>>>(ATT, XC, idx, cidx, bn_g, bn_b, bn_mean, bn_var, VIS);
    k_propagate<<<BB * 128, 128, 0, stream>>>(center1, center2, XC, VIS, XFN);

    // --- final adapter + slice ---
    k_build_xfinal<<<(M1 * DD + 255) / 256, 256, 0, stream>>>(XC, XFN, XFIN);
    k_gemm<<<dim3(1, 139), 256, 0, stream>>>(XFIN, ad1_dw, ad1_db, (const float*)nullptr, T16, M1, 16, 384, 1);
    k_final<<<BB * 129, 128, 0, stream>>>(T16, ad1_uw, ad1_ub, XFIN, out_x);
}

// Round 3
// 492.239 us; speedup vs baseline: 1.6044x; 1.6044x over previous
//
#include <hip/hip_runtime.h>
#include <hip/hip_bf16.h>

typedef __hip_bfloat16 bf16;
typedef __attribute__((ext_vector_type(8))) short short8;
typedef __attribute__((ext_vector_type(4))) float f32x4;

#define DEV static __device__ __forceinline__

DEV float b2f(bf16 v) { return __bfloat162float(v); }
DEV bf16 f2b(float v) { return __float2bfloat16(v); }
DEV unsigned short f2bu(float v) { return __builtin_bit_cast(unsigned short, __float2bfloat16(v)); }
DEV float u2f(unsigned short u) { return __uint_as_float(((unsigned int)u) << 16); }
DEV float gelu(float x) { return 0.5f * x * (1.0f + erff(x * 0.70710678118654752f)); }

// Problem constants
#define BB 64
#define NT 139     // 1 + T + G1
#define DD 384
#define TT 10
#define HH 6
#define GG 138     // G1 + T
#define M1 8896    // BB*NT = 64*139, multiple of 64
#define MG 8832    // BB*GG = 64*138, multiple of 64
#define NGRP 2048  // BB*S
#define SCALE 0.125f

// Workspace byte offsets (proven layout; + bf16 weights block = 90.4 MB)
#define XC_OFF   0UL          // f32 8896x384 residual stream, live whole call
#define VIS_OFF  13664256UL   // f32 2048x384
#define XNB_OFF  16809984UL   // bf16 8896x384: LN out; attn1 o; dead after consumer
#define XFN_OFF  23642112UL   // f32 8896x384: fc2 out; x_prop
#define T16_OFF  37306368UL   // f32 8896x16 (unused after adapter fusion; offset kept)
#define BIG1_OFF 37875712UL   // bf16 8896x1152: qkv / qkv1
#define BIG2_OFF 58372096UL   // bf16 8896x1536 fc1h / bf16 32768x384 o1 / f32 x_final
#define ATT_OFF  XNB_OFF      // bf16 32768x384 proj1 out (overlays dead XNB..BIG1 prefix)
#define WB_OFF   85700608UL   // bf16 2359296: pre-converted weights

// bf16 weight block element offsets
#define WB_QKV   0
#define WB_PROJ  442368
#define WB_FC1   589824
#define WB_FC2   1179648
#define WB_QKV1  1769472
#define WB_PROJ1 2211840
#define WB_TOTAL 2359296

#define OUT_X 3170304  // 64*129*384

DEV float4 ld4(const float* p) { return *(const float4*)p; }
DEV float4 ld4(const bf16* p) {
    ushort4 u = *(const ushort4*)p;
    return make_float4(u2f(u.x), u2f(u.y), u2f(u.z), u2f(u.w));
}
DEV void stc(float* p, float v) { *p = v; }
DEV void stc(bf16* p, float v) { *p = f2b(v); }

// ---------- weights f32 -> bf16 (once per call) ----------
__global__ __launch_bounds__(256) void k_wconv(const float* __restrict__ w0, const float* __restrict__ w1,
                                               const float* __restrict__ w2, const float* __restrict__ w3,
                                               const float* __restrict__ w4, const float* __restrict__ w5,
                                               bf16* __restrict__ dst) {
    int i4 = (blockIdx.x * 256 + threadIdx.x) * 4;
    if (i4 >= WB_TOTAL) return;
    const float* s; int off;
    if (i4 < WB_PROJ)       { s = w0; off = WB_QKV; }
    else if (i4 < WB_FC1)   { s = w1; off = WB_PROJ; }
    else if (i4 < WB_FC2)   { s = w2; off = WB_FC1; }
    else if (i4 < WB_QKV1)  { s = w3; off = WB_FC2; }
    else if (i4 < WB_PROJ1) { s = w4; off = WB_QKV1; }
    else                    { s = w5; off = WB_PROJ1; }
    float4 v = *(const float4*)(s + (i4 - off));
    ushort4 u;
    u.x = f2bu(v.x); u.y = f2bu(v.y); u.z = f2bu(v.z); u.w = f2bu(v.w);
    *(ushort4*)((unsigned short*)dst + i4) = u;
}

// ---------- fused concat + LN1: xc row built AND layernormed -> xnb (one pass) ----------
__global__ __launch_bounds__(128) void k_build_ln(const float* __restrict__ x, const float* __restrict__ pe,
                                                  const float* __restrict__ g, const float* __restrict__ bta,
                                                  float* __restrict__ xc, bf16* __restrict__ dst) {
    int r = blockIdx.x;
    int n = r % NT, b = r / NT;
    const float* p;
    if (n == 0)       p = x + (size_t)(b * 129) * DD;
    else if (n <= TT) p = pe + (size_t)(n - 1) * DD;
    else              p = x + (size_t)(b * 129 + n - TT) * DD;
    int t = threadIdx.x;
    float v0 = p[t], v1 = p[t + 128], v2 = p[t + 256];
    float* xr = xc + (size_t)r * DD;
    xr[t] = v0; xr[t + 128] = v1; xr[t + 256] = v2;
    __shared__ float red[4];
    float s = v0 + v1 + v2;
    for (int off = 32; off; off >>= 1) s += __shfl_down(s, off, 64);
    if ((t & 63) == 0) red[t >> 6] = s;
    __syncthreads();
    float mean = (red[0] + red[1]) * (1.0f / 384.0f);
    float d0 = v0 - mean, d1 = v1 - mean, d2 = v2 - mean;
    float s2 = d0 * d0 + d1 * d1 + d2 * d2;
    for (int off = 32; off; off >>= 1) s2 += __shfl_down(s2, off, 64);
    if ((t & 63) == 0) red[2 + (t >> 6)] = s2;
    __syncthreads();
    float rstd = rsqrtf((red[2] + red[3]) * (1.0f / 384.0f) + 1e-5f);
    bf16* q = dst + (size_t)r * DD;
    q[t]       = f2b(d0 * rstd * g[t]       + bta[t]);
    q[t + 128] = f2b(d1 * rstd * g[t + 128] + bta[t + 128]);
    q[t + 256] = f2b(d2 * rstd * g[t + 256] + bta[t + 256]);
}

// ---------- layernorm f32 -> bf16 (mode 1: gather row (r/138)*139+1+(r%138)) ----------
__global__ __launch_bounds__(128) void k_layernorm(const float* __restrict__ src, bf16* __restrict__ dst,
                                                   const float* __restrict__ g, const float* __restrict__ bta,
                                                   int mode) {
    int r = blockIdx.x;
    int srow = r;
    if (mode) srow = (r / GG) * NT + 1 + (r % GG);
    const float* p = src + (size_t)srow * DD;
    int t = threadIdx.x;
    float v0 = p[t], v1 = p[t + 128], v2 = p[t + 256];
    __shared__ float red[4];
    float s = v0 + v1 + v2;
    for (int off = 32; off; off >>= 1) s += __shfl_down(s, off, 64);
    if ((t & 63) == 0) red[t >> 6] = s;
    __syncthreads();
    float mean = (red[0] + red[1]) * (1.0f / 384.0f);
    float d0 = v0 - mean, d1 = v1 - mean, d2 = v2 - mean;
    float s2 = d0 * d0 + d1 * d1 + d2 * d2;
    for (int off = 32; off; off >>= 1) s2 += __shfl_down(s2, off, 64);
    if ((t & 63) == 0) red[2 + (t >> 6)] = s2;
    __syncthreads();
    float rstd = rsqrtf((red[2] + red[3]) * (1.0f / 384.0f) + 1e-5f);
    bf16* q = dst + (size_t)r * DD;
    q[t]       = f2b(d0 * rstd * g[t]       + bta[t]);
    q[t + 128] = f2b(d1 * rstd * g[t + 128] + bta[t + 128]);
    q[t + 256] = f2b(d2 * rstd * g[t + 256] + bta[t + 256]);
}

// ---------- MFMA GEMM: C[M,N] = act(A[M,K]bf16 @ W[N,K]^T bf16 + bias) (+res) ----------
// BM=64 BN=64 BK=64, 4 waves (2x2) each 32x32 via 2x2x(2 ks) 16x16x32 MFMAs.
// 2-stage register prefetch: load tile k+1 to regs while computing tile k from LDS.
// Requires: M % 64 == 0 (true for all call sites), N % 64 == 0, K % 64 == 0.
template <typename TC>
__global__ __launch_bounds__(256) void mf_gemm(const bf16* __restrict__ A, const bf16* __restrict__ W,
                                               const float* __restrict__ bias, const float* __restrict__ res,
                                               TC* __restrict__ C, int M, int N, int K, int act) {
    __shared__ bf16 As[64][72];
    __shared__ bf16 Ws[64][72];
    int t = threadIdx.x;
    int m0 = blockIdx.y * 64, n0 = blockIdx.x * 64;
    int lane = t & 63, wv = t >> 6;
    int wm = (wv >> 1) * 32, wn = (wv & 1) * 32;
    int fr = lane & 15, fq = lane >> 4;
    int sr = t >> 2, sc = (t & 3) * 16;   // staging: 4 thr/row, 32B (2 x uint4) each
    const bf16* pa = A + (size_t)(m0 + sr) * K + sc;
    const bf16* pw = W + (size_t)(n0 + sr) * K + sc;
    uint4 ra0 = *(const uint4*)pa;
    uint4 ra1 = *(const uint4*)(pa + 8);
    uint4 rw0 = *(const uint4*)pw;
    uint4 rw1 = *(const uint4*)(pw + 8);
    f32x4 acc[2][2] = {};
    int k0 = 0;
    for (;;) {
        *(uint4*)&As[sr][sc] = ra0; *(uint4*)&As[sr][sc + 8] = ra1;
        *(uint4*)&Ws[sr][sc] = rw0; *(uint4*)&Ws[sr][sc + 8] = rw1;
        __syncthreads();
        k0 += 64;
        bool more = (k0 < K);
        if (more) {
            ra0 = *(const uint4*)(pa + k0); ra1 = *(const uint4*)(pa + k0 + 8);
            rw0 = *(const uint4*)(pw + k0); rw1 = *(const uint4*)(pw + k0 + 8);
        }
#pragma unroll
        for (int ks = 0; ks < 2; ++ks) {
            short8 a0 = *(const short8*)&As[wm + fr][ks * 32 + fq * 8];
            short8 a1 = *(const short8*)&As[wm + 16 + fr][ks * 32 + fq * 8];
            short8 b0 = *(const short8*)&Ws[wn + fr][ks * 32 + fq * 8];
            short8 b1 = *(const short8*)&Ws[wn + 16 + fr][ks * 32 + fq * 8];
            acc[0][0] = __builtin_amdgcn_mfma_f32_16x16x32_bf16(a0, b0, acc[0][0], 0, 0, 0);
            acc[0][1] = __builtin_amdgcn_mfma_f32_16x16x32_bf16(a0, b1, acc[0][1], 0, 0, 0);
            acc[1][0] = __builtin_amdgcn_mfma_f32_16x16x32_bf16(a1, b0, acc[1][0], 0, 0, 0);
            acc[1][1] = __builtin_amdgcn_mfma_f32_16x16x32_bf16(a1, b1, acc[1][1], 0, 0, 0);
        }
        if (!more) break;
        __syncthreads();
    }
#pragma unroll
    for (int i = 0; i < 2; ++i) {
#pragma unroll
        for (int r = 0; r < 4; ++r) {
            int row = m0 + wm + i * 16 + fq * 4 + r;
            size_t ro = (size_t)row * N;
#pragma unroll
            for (int j = 0; j < 2; ++j) {
                int col = n0 + wn + j * 16 + fr;
                float c = acc[i][j][r];
                if (bias) c += bias[col];
                if (act == 1) c = gelu(c);
                if (res) c += res[ro + col];
                stc(&C[ro + col], c);
            }
        }
    }
}

// ---------- fused N=16 adapter: down(gelu) + up + combine, one block per row ----------
// mode 0: xc[r] += 0.7*(gelu(xfn[r]@dw^T+db)@uw^T+ub) + xfn[r]      (grid M1)
// mode 1: out[rb] = gelu(xf[src]@dw^T+db)@uw^T+ub + xf[src]          (grid BB*129, slice remap)
__global__ __launch_bounds__(128) void k_adapter(const float* __restrict__ srcbuf,
                                                 const float* __restrict__ dw, const float* __restrict__ db,
                                                 const float* __restrict__ uw, const float* __restrict__ ub,
                                                 float* __restrict__ dst, int mode) {
    int rb = blockIdx.x, t = threadIdx.x;
    const float* s;
    float* d;
    if (mode == 0) {
        s = srcbuf + (size_t)rb * DD;
        d = dst + (size_t)rb * DD;
    } else {
        int b = rb / 129, no = rb % 129;
        int srow = b * NT + (no == 0 ? 0 : no + TT);
        s = srcbuf + (size_t)srow * DD;
        d = dst + (size_t)rb * DD;
    }
    __shared__ float tl[16];
    // 16 groups x 8 lanes: group g computes dot(s, dw[g]) over 384 elems (48/lane)
    int g = t >> 3, sub = t & 7;
    const float* wg = dw + g * DD + sub * 48;
    const float* sg = s + sub * 48;
    float part = 0.f;
#pragma unroll
    for (int j = 0; j < 12; ++j) {
        float4 a = *(const float4*)(sg + j * 4);
        float4 w = *(const float4*)(wg + j * 4);
        part += a.x * w.x + a.y * w.y + a.z * w.z + a.w * w.w;
    }
    part += __shfl_xor(part, 1, 64);
    part += __shfl_xor(part, 2, 64);
    part += __shfl_xor(part, 4, 64);
    if (sub == 0) tl[g] = gelu(part + db[g]);
    __syncthreads();
    for (int dd = t; dd < DD; dd += 128) {
        float acc = 0.f;
#pragma unroll
        for (int c = 0; c < 4; ++c) {
            float4 u = *(const float4*)(uw + dd * 16 + c * 4);
            acc += tl[c * 4 + 0] * u.x + tl[c * 4 + 1] * u.y
                 + tl[c * 4 + 2] * u.z + tl[c * 4 + 3] * u.w;
        }
        acc += ub[dd];
        if (mode == 0) d[dd] += 0.7f * acc + s[dd];
        else           d[dd] = acc + s[dd];
    }
}

// ---------- stage-1 attention (MFMA): one block per (b,h) ----------
__global__ __launch_bounds__(256) void k_attn1(const bf16* __restrict__ qkv, bf16* __restrict__ o_out,
                                               float* __restrict__ attn_out) {
    int bh = blockIdx.x;
    int b = bh / HH, h = bh % HH;
    __shared__ unsigned short Kl[144][72];
    __shared__ unsigned short Vt[64][160];
    __shared__ unsigned short Pl[4][16][160];
    int t = threadIdx.x;
    int lane = t & 63, wv = t >> 6;
    int fr = lane & 15, fq = lane >> 4;
    const unsigned short* q16 = (const unsigned short*)qkv;
    size_t base = (size_t)b * NT * 1152;

    uint4 z4 = make_uint4(0, 0, 0, 0);
    for (int i = t * 8; i < 64 * 160; i += 2048) *(uint4*)(&Vt[0][0] + i) = z4;
    for (int i = t * 8; i < 4 * 16 * 160; i += 2048) *(uint4*)(&Pl[0][0][0] + i) = z4;
    for (int i = t; i < 144 * 8; i += 256) {
        int row = i >> 3, ch = (i & 7) * 8;
        uint4 v = z4;
        if (row < NT) v = *(const uint4*)(q16 + base + row * 1152 + 384 + h * 64 + ch);
        *(uint4*)&Kl[row][ch] = v;
    }
    for (int i = t; i < NT * 16; i += 256) {
        int m = i >> 4, dq = (i & 15) * 4;
        ushort4 v = *(const ushort4*)(q16 + base + m * 1152 + 768 + h * 64 + dq);
        Vt[dq + 0][m] = v.x; Vt[dq + 1][m] = v.y;
        Vt[dq + 2][m] = v.z; Vt[dq + 3][m] = v.w;
    }
    __syncthreads();

    for (int nt = wv; nt < 9; nt += 4) {
        int n0 = nt * 16;
        int arow = n0 + fr; if (arow > NT - 1) arow = NT - 1;
        const unsigned short* qp = q16 + base + (size_t)arow * 1152 + h * 64 + fq * 8;
        short8 a0 = *(const short8*)qp;
        short8 a1 = *(const short8*)(qp + 32);
        f32x4 s[9] = {};
#pragma unroll
        for (int mt = 0; mt < 9; ++mt) {
            short8 b0 = *(const short8*)&Kl[mt * 16 + fr][fq * 8];
            short8 b1 = *(const short8*)&Kl[mt * 16 + fr][32 + fq * 8];
            s[mt] = __builtin_amdgcn_mfma_f32_16x16x32_bf16(a0, b0, s[mt], 0, 0, 0);
            s[mt] = __builtin_amdgcn_mfma_f32_16x16x32_bf16(a1, b1, s[mt], 0, 0, 0);
        }
#pragma unroll
        for (int r = 0; r < 4; ++r) {
            float e[9];
            float mx = -1e30f;
#pragma unroll
            for (int mt = 0; mt < 9; ++mt) {
                int col = mt * 16 + fr;
                float v = (col < NT) ? s[mt][r] * SCALE : -1e30f;
                e[mt] = v;
                mx = fmaxf(mx, v);
            }
#pragma unroll
            for (int off = 1; off < 16; off <<= 1) mx = fmaxf(mx, __shfl_xor(mx, off, 64));
            float sm = 0.f;
#pragma unroll
            for (int mt = 0; mt < 9; ++mt) { e[mt] = __expf(e[mt] - mx); sm += e[mt]; }
#pragma unroll
            for (int off = 1; off < 16; off <<= 1) sm += __shfl_xor(sm, off, 64);
            float inv = 1.0f / sm;
            int n = n0 + fq * 4 + r;
            bool nv = n < NT;
            size_t ab = ((size_t)(b * HH + h) * NT + n) * NT;
#pragma unroll
            for (int mt = 0; mt < 9; ++mt) {
                float p = e[mt] * inv;
                int col = mt * 16 + fr;
                if (nv && col < NT) attn_out[ab + col] = p;
                Pl[wv][fq * 4 + r][col] = f2bu(p);
            }
        }
        __syncthreads();
        f32x4 oac[4] = {};
#pragma unroll
        for (int ks = 0; ks < 5; ++ks) {
            short8 ap = *(const short8*)&Pl[wv][fr][ks * 32 + fq * 8];
#pragma unroll
            for (int dt = 0; dt < 4; ++dt) {
                short8 bv = *(const short8*)&Vt[dt * 16 + fr][ks * 32 + fq * 8];
                oac[dt] = __builtin_amdgcn_mfma_f32_16x16x32_bf16(ap, bv, oac[dt], 0, 0, 0);
            }
        }
#pragma unroll
        for (int dt = 0; dt < 4; ++dt)
#pragma unroll
            for (int r = 0; r < 4; ++r) {
                int n = n0 + fq * 4 + r;
                if (n < NT)
                    o_out[((size_t)(b * NT + n)) * DD + h * 64 + dt * 16 + fr] = f2b(oac[dt][r]);
            }
    }
}

// ---------- stage-2 per-group attention (MFMA): one wave per group ----------
__global__ __launch_bounds__(64) void k_attn2(const bf16* __restrict__ qkv, const int* __restrict__ idx,
                                              bf16* __restrict__ o1) {
    int g = blockIdx.x;
    __shared__ unsigned short Vt2[64][40];
    __shared__ unsigned short P2[16][40];
    __shared__ int ridx[16];
    int t = threadIdx.x;
    int fr = t & 15, fq = t >> 4;
    const unsigned short* q16 = (const unsigned short*)qkv;
    if (t < 16) ridx[t] = idx[g * 16 + t];
    uint4 z4 = make_uint4(0, 0, 0, 0);
    for (int i = t * 8; i < 64 * 40; i += 512) *(uint4*)(&Vt2[0][0] + i) = z4;
    for (int i = t * 8; i < 16 * 40; i += 512) *(uint4*)(&P2[0][0] + i) = z4;
    __syncthreads();
    size_t qb = (size_t)ridx[fr] * 1152;
    for (int h = 0; h < HH; ++h) {
        for (int i = t; i < 256; i += 64) {
            int m = i >> 4, dq = (i & 15) * 4;
            ushort4 v = *(const ushort4*)(q16 + (size_t)ridx[m] * 1152 + 768 + h * 64 + dq);
            Vt2[dq + 0][m] = v.x; Vt2[dq + 1][m] = v.y;
            Vt2[dq + 2][m] = v.z; Vt2[dq + 3][m] = v.w;
        }
        __syncthreads();
        const unsigned short* qp = q16 + qb + h * 64 + fq * 8;
        const unsigned short* kp = q16 + qb + 384 + h * 64 + fq * 8;
        short8 a0 = *(const short8*)qp;
        short8 a1 = *(const short8*)(qp + 32);
        short8 b0 = *(const short8*)kp;
        short8 b1 = *(const short8*)(kp + 32);
        f32x4 s = {};
        s = __builtin_amdgcn_mfma_f32_16x16x32_bf16(a0, b0, s, 0, 0, 0);
        s = __builtin_amdgcn_mfma_f32_16x16x32_bf16(a1, b1, s, 0, 0, 0);
#pragma unroll
        for (int r = 0; r < 4; ++r) {
            float v = s[r] * SCALE;
            float mx = v;
#pragma unroll
            for (int off = 1; off < 16; off <<= 1) mx = fmaxf(mx, __shfl_xor(mx, off, 64));
            float e = __expf(v - mx), sm = e;
#pragma unroll
            for (int off = 1; off < 16; off <<= 1) sm += __shfl_xor(sm, off, 64);
            P2[fq * 4 + r][fr] = f2bu(e / sm);
        }
        __syncthreads();
        short8 ap = *(const short8*)&P2[fr][fq * 8];
        f32x4 oac[4] = {};
#pragma unroll
        for (int dt = 0; dt < 4; ++dt) {
            short8 bv = *(const short8*)&Vt2[dt * 16 + fr][fq * 8];
            oac[dt] = __builtin_amdgcn_mfma_f32_16x16x32_bf16(ap, bv, oac[dt], 0, 0, 0);
        }
#pragma unroll
        for (int dt = 0; dt < 4; ++dt)
#pragma unroll
            for (int r = 0; r < 4; ++r)
                o1[((size_t)(g * 16 + fq * 4 + r)) * DD + h * 64 + dt * 16 + fr] = f2b(oac[dt][r]);
        __syncthreads();
    }
}

// ---------- group residual + max + BN + GELU + centers -> vis ----------
__global__ __launch_bounds__(128) void k_groupmax(const bf16* __restrict__ att, const float* __restrict__ xc,
                                                  const int* __restrict__ idx, const int* __restrict__ cidx,
                                                  const float* __restrict__ bg, const float* __restrict__ bb,
                                                  const float* __restrict__ bmean, const float* __restrict__ bvar,
                                                  float* __restrict__ vis) {
    int g = blockIdx.x, t = threadIdx.x;
    __shared__ int rows[16];
    __shared__ int crow;
    if (t < 16) { int r = idx[g * 16 + t]; rows[t] = (r / GG) * NT + 1 + (r % GG); }
    if (t == 16) { int r = cidx[g]; crow = (r / GG) * NT + 1 + (r % GG); }
    __syncthreads();
    for (int d = t; d < DD; d += 128) {
        float m = -INFINITY;
#pragma unroll
        for (int j = 0; j < 16; ++j) {
            float v = b2f(att[((size_t)(g * 16 + j)) * DD + d]) + xc[(size_t)rows[j] * DD + d];
            m = fmaxf(m, v);
        }
        float bn = (m - bmean[d]) * rsqrtf(bvar[d] + 1e-5f) * bg[d] + bb[d];
        bn = gelu(bn);
        vis[(size_t)g * DD + d] = bn + 0.3f * xc[(size_t)crow * DD + d];
    }
}

// ---------- propagate ----------
__global__ __launch_bounds__(128) void k_propagate(const float* __restrict__ c1, const float* __restrict__ c2,
                                                   const float* __restrict__ xc, const float* __restrict__ vis,
                                                   float* __restrict__ xp) {
    int blk = blockIdx.x;
    int b = blk >> 7, i = blk & 127;
    int t = threadIdx.x;
    __shared__ float wl[32];
    __shared__ float wsum;
    if (t < 32) {
        float dx = c1[(b * 128 + i) * 3 + 0] - c2[(b * 32 + t) * 3 + 0];
        float dy = c1[(b * 128 + i) * 3 + 1] - c2[(b * 32 + t) * 3 + 1];
        float dz = c1[(b * 128 + i) * 3 + 2] - c2[(b * 32 + t) * 3 + 2];
        wl[t] = 1.0f / (dx * dx + dy * dy + dz * dz + 1e-8f);
    }
    __syncthreads();
    if (t == 0) {
        float s = 0.f;
        for (int j = 0; j < 32; ++j) s += wl[j];
        wsum = s;
    }
    __syncthreads();
    float sc = 0.3f / wsum;
    for (int d = t; d < DD; d += 128) {
        float acc = 0.f;
#pragma unroll 8
        for (int j = 0; j < 32; ++j) acc += wl[j] * vis[((size_t)(b * 32 + j)) * DD + d];
        xp[((size_t)(b * 128 + i)) * DD + d] = xc[((size_t)(b * NT + 11 + i)) * DD + d] + sc * acc;
    }
}

// ---------- build x_final = [cls, prompt, x_prop] ----------
__global__ __launch_bounds__(256) void k_build_xfinal(const float* __restrict__ xc, const float* __restrict__ xp,
                                                      float* __restrict__ xf) {
    int i = blockIdx.x * 256 + threadIdx.x;
    if (i >= M1 * DD) return;
    int d = i % DD, r = i / DD, n = r % NT, b = r / NT;
    xf[i] = (n < 11) ? xc[i] : xp[((size_t)(b * 128 + n - 11)) * DD + d];
}

extern "C" void kernel_launch(void* const* d_in, const int* in_sizes, int n_in,
                              void* d_out, int out_size, void* d_ws, size_t ws_size,
                              hipStream_t stream) {
    const float* x_in    = (const float*)d_in[0];
    const float* center1 = (const float*)d_in[2];
    const float* center2 = (const float*)d_in[3];
    const int*   idx     = (const int*)d_in[5];
    const int*   cidx    = (const int*)d_in[6];
    const float* ln1_g   = (const float*)d_in[9];
    const float* ln1_b   = (const float*)d_in[10];
    const float* ln2_g   = (const float*)d_in[11];
    const float* ln2_b   = (const float*)d_in[12];
    const float* qkv_w   = (const float*)d_in[13];
    const float* proj_w  = (const float*)d_in[14];
    const float* proj_b  = (const float*)d_in[15];
    const float* fc1_w   = (const float*)d_in[16];
    const float* fc1_b   = (const float*)d_in[17];
    const float* fc2_w   = (const float*)d_in[18];
    const float* fc2_b   = (const float*)d_in[19];
    const float* ad_dw   = (const float*)d_in[20];
    const float* ad_db   = (const float*)d_in[21];
    const float* ad_uw   = (const float*)d_in[22];
    const float* ad_ub   = (const float*)d_in[23];
    const float* ad1_dw  = (const float*)d_in[24];
    const float* ad1_db  = (const float*)d_in[25];
    const float* ad1_uw  = (const float*)d_in[26];
    const float* ad1_ub  = (const float*)d_in[27];
    const float* prompt  = (const float*)d_in[28];
    const float* bn_g    = (const float*)d_in[29];
    const float* bn_b    = (const float*)d_in[30];
    const float* bn_mean = (const float*)d_in[31];
    const float* bn_var  = (const float*)d_in[32];
    const float* qkv1_w  = (const float*)d_in[33];
    const float* proj1_w = (const float*)d_in[34];
    const float* proj1_b = (const float*)d_in[35];
    const float* ln3_g   = (const float*)d_in[36];
    const float* ln3_b   = (const float*)d_in[37];

    char* wsb = (char*)d_ws;
    float* XC   = (float*)(wsb + XC_OFF);
    float* VIS  = (float*)(wsb + VIS_OFF);
    bf16*  XNB  = (bf16*)(wsb + XNB_OFF);
    float* XFN  = (float*)(wsb + XFN_OFF);
    bf16*  BIG1 = (bf16*)(wsb + BIG1_OFF);
    bf16*  BIG2 = (bf16*)(wsb + BIG2_OFF);
    float* XFIN = (float*)(wsb + BIG2_OFF);
    bf16*  ATT  = (bf16*)(wsb + ATT_OFF);
    bf16*  WB   = (bf16*)(wsb + WB_OFF);

    float* out_x    = (float*)d_out;
    float* out_attn = out_x + OUT_X;

    // --- weights -> bf16 (graph-safe: every call) ---
    k_wconv<<<(WB_TOTAL / 4 + 255) / 256, 256, 0, stream>>>(qkv_w, proj_w, fc1_w, fc2_w, qkv1_w, proj1_w, WB);

    // --- stage 1 ---
    k_build_ln<<<M1, 128, 0, stream>>>(x_in, prompt, ln1_g, ln1_b, XC, XNB);
    mf_gemm<<<dim3(18, 139), 256, 0, stream>>>(XNB, WB + WB_QKV, (const float*)nullptr, (const float*)nullptr, BIG1, M1, 1152, 384, 0);
    k_attn1<<<BB * HH, 256, 0, stream>>>(BIG1, XNB, out_attn);
    mf_gemm<<<dim3(6, 139), 256, 0, stream>>>(XNB, WB + WB_PROJ, proj_b, XC, XC, M1, 384, 384, 0);
    k_layernorm<<<M1, 128, 0, stream>>>(XC, XNB, ln2_g, ln2_b, 0);
    mf_gemm<<<dim3(24, 139), 256, 0, stream>>>(XNB, WB + WB_FC1, fc1_b, (const float*)nullptr, BIG2, M1, 1536, 384, 1);
    mf_gemm<<<dim3(6, 139), 256, 0, stream>>>(BIG2, WB + WB_FC2, fc2_b, (const float*)nullptr, XFN, M1, 384, 1536, 0);
    k_adapter<<<M1, 128, 0, stream>>>(XFN, ad_dw, ad_db, ad_uw, ad_ub, XC, 0);

    // --- stage 2 (group attention on 8832 unique rows) ---
    k_layernorm<<<MG, 128, 0, stream>>>(XC, XNB, ln3_g, ln3_b, 1);
    mf_gemm<<<dim3(18, 138), 256, 0, stream>>>(XNB, WB + WB_QKV1, (const float*)nullptr, (const float*)nullptr, BIG1, MG, 1152, 384, 0);
    k_attn2<<<NGRP, 64, 0, stream>>>(BIG1, idx, BIG2);
    mf_gemm<<<dim3(6, 512), 256, 0, stream>>>(BIG2, WB + WB_PROJ1, proj1_b, (const float*)nullptr, ATT, NGRP * 16, 384, 384, 0);
    k_groupmax<<<NGRP, 128, 0, stream>>>(ATT, XC, idx, cidx, bn_g, bn_b, bn_mean, bn_var, VIS);
    k_propagate<<<BB * 128, 128, 0, stream>>>(center1, center2, XC, VIS, XFN);

    // --- final adapter + slice ---
    k_build_xfinal<<<(M1 * DD + 255) / 256, 256, 0, stream>>>(XC, XFN, XFIN);
    k_adapter<<<BB * 129, 128, 0, stream>>>(XFIN, ad1_dw, ad1_db, ad1_uw, ad1_ub, out_x, 1);
}

// Round 5
// 491.275 us; speedup vs baseline: 1.6075x; 1.0020x over previous
//
#include <hip/hip_runtime.h>
#include <hip/hip_bf16.h>

typedef __hip_bfloat16 bf16;
typedef __attribute__((ext_vector_type(8))) short short8;
typedef __attribute__((ext_vector_type(4))) float f32x4;

#define DEV static __device__ __forceinline__

DEV float b2f(bf16 v) { return __bfloat162float(v); }
DEV bf16 f2b(float v) { return __float2bfloat16(v); }
DEV unsigned short f2bu(float v) { return __builtin_bit_cast(unsigned short, __float2bfloat16(v)); }
DEV float u2f(unsigned short u) { return __uint_as_float(((unsigned int)u) << 16); }
DEV float gelu(float x) { return 0.5f * x * (1.0f + erff(x * 0.70710678118654752f)); }

// Problem constants
#define BB 64
#define NT 139     // 1 + T + G1
#define DD 384
#define TT 10
#define HH 6
#define GG 138     // G1 + T
#define M1 8896    // BB*NT = 64*139, multiple of 64
#define MG 8832    // BB*GG = 64*138, multiple of 64
#define NGRP 2048  // BB*S
#define SCALE 0.125f

// Workspace byte offsets (proven layout; + bf16 weights block = 90.4 MB)
#define XC_OFF   0UL          // f32 8896x384 residual stream, live whole call
#define VIS_OFF  13664256UL   // f32 2048x384
#define XNB_OFF  16809984UL   // bf16 8896x384: LN out; attn1 o; dead after consumer
#define XFN_OFF  23642112UL   // f32 8896x384: fc2 out; x_prop
#define BIG1_OFF 37875712UL   // bf16 8896x1152: qkv / qkv1
#define BIG2_OFF 58372096UL   // bf16 8896x1536 fc1h / bf16 32768x384 o1
#define ATT_OFF  XNB_OFF      // bf16 32768x384 proj1 out (overlays dead XNB..BIG1 prefix)
#define WB_OFF   85700608UL   // bf16 2359296: pre-converted weights

// bf16 weight block element offsets
#define WB_QKV   0
#define WB_PROJ  442368
#define WB_FC1   589824
#define WB_FC2   1179648
#define WB_QKV1  1769472
#define WB_PROJ1 2211840
#define WB_TOTAL 2359296

#define OUT_X 3170304  // 64*129*384

DEV float4 ld4(const float* p) { return *(const float4*)p; }
DEV float4 ld4(const bf16* p) {
    ushort4 u = *(const ushort4*)p;
    return make_float4(u2f(u.x), u2f(u.y), u2f(u.z), u2f(u.w));
}
DEV void stc(float* p, float v) { *p = v; }
DEV void stc(bf16* p, float v) { *p = f2b(v); }

// ---------- weights f32 -> bf16 (once per call) ----------
__global__ __launch_bounds__(256) void k_wconv(const float* __restrict__ w0, const float* __restrict__ w1,
                                               const float* __restrict__ w2, const float* __restrict__ w3,
                                               const float* __restrict__ w4, const float* __restrict__ w5,
                                               bf16* __restrict__ dst) {
    int i4 = (blockIdx.x * 256 + threadIdx.x) * 4;
    if (i4 >= WB_TOTAL) return;
    const float* s; int off;
    if (i4 < WB_PROJ)       { s = w0; off = WB_QKV; }
    else if (i4 < WB_FC1)   { s = w1; off = WB_PROJ; }
    else if (i4 < WB_FC2)   { s = w2; off = WB_FC1; }
    else if (i4 < WB_QKV1)  { s = w3; off = WB_FC2; }
    else if (i4 < WB_PROJ1) { s = w4; off = WB_QKV1; }
    else                    { s = w5; off = WB_PROJ1; }
    float4 v = *(const float4*)(s + (i4 - off));
    ushort4 u;
    u.x = f2bu(v.x); u.y = f2bu(v.y); u.z = f2bu(v.z); u.w = f2bu(v.w);
    *(ushort4*)((unsigned short*)dst + i4) = u;
}

// ---------- fused concat + LN1: xc row built AND layernormed -> xnb (one pass) ----------
__global__ __launch_bounds__(128) void k_build_ln(const float* __restrict__ x, const float* __restrict__ pe,
                                                  const float* __restrict__ g, const float* __restrict__ bta,
                                                  float* __restrict__ xc, bf16* __restrict__ dst) {
    int r = blockIdx.x;
    int n = r % NT, b = r / NT;
    const float* p;
    if (n == 0)       p = x + (size_t)(b * 129) * DD;
    else if (n <= TT) p = pe + (size_t)(n - 1) * DD;
    else              p = x + (size_t)(b * 129 + n - TT) * DD;
    int t = threadIdx.x;
    float v0 = p[t], v1 = p[t + 128], v2 = p[t + 256];
    float* xr = xc + (size_t)r * DD;
    xr[t] = v0; xr[t + 128] = v1; xr[t + 256] = v2;
    __shared__ float red[4];
    float s = v0 + v1 + v2;
    for (int off = 32; off; off >>= 1) s += __shfl_down(s, off, 64);
    if ((t & 63) == 0) red[t >> 6] = s;
    __syncthreads();
    float mean = (red[0] + red[1]) * (1.0f / 384.0f);
    float d0 = v0 - mean, d1 = v1 - mean, d2 = v2 - mean;
    float s2 = d0 * d0 + d1 * d1 + d2 * d2;
    for (int off = 32; off; off >>= 1) s2 += __shfl_down(s2, off, 64);
    if ((t & 63) == 0) red[2 + (t >> 6)] = s2;
    __syncthreads();
    float rstd = rsqrtf((red[2] + red[3]) * (1.0f / 384.0f) + 1e-5f);
    bf16* q = dst + (size_t)r * DD;
    q[t]       = f2b(d0 * rstd * g[t]       + bta[t]);
    q[t + 128] = f2b(d1 * rstd * g[t + 128] + bta[t + 128]);
    q[t + 256] = f2b(d2 * rstd * g[t + 256] + bta[t + 256]);
}

// ---------- layernorm f32 -> bf16 (mode 1: gather row (r/138)*139+1+(r%138)) ----------
__global__ __launch_bounds__(128) void k_layernorm(const float* __restrict__ src, bf16* __restrict__ dst,
                                                   const float* __restrict__ g, const float* __restrict__ bta,
                                                   int mode) {
    int r = blockIdx.x;
    int srow = r;
    if (mode) srow = (r / GG) * NT + 1 + (r % GG);
    const float* p = src + (size_t)srow * DD;
    int t = threadIdx.x;
    float v0 = p[t], v1 = p[t + 128], v2 = p[t + 256];
    __shared__ float red[4];
    float s = v0 + v1 + v2;
    for (int off = 32; off; off >>= 1) s += __shfl_down(s, off, 64);
    if ((t & 63) == 0) red[t >> 6] = s;
    __syncthreads();
    float mean = (red[0] + red[1]) * (1.0f / 384.0f);
    float d0 = v0 - mean, d1 = v1 - mean, d2 = v2 - mean;
    float s2 = d0 * d0 + d1 * d1 + d2 * d2;
    for (int off = 32; off; off >>= 1) s2 += __shfl_down(s2, off, 64);
    if ((t & 63) == 0) red[2 + (t >> 6)] = s2;
    __syncthreads();
    float rstd = rsqrtf((red[2] + red[3]) * (1.0f / 384.0f) + 1e-5f);
    bf16* q = dst + (size_t)r * DD;
    q[t]       = f2b(d0 * rstd * g[t]       + bta[t]);
    q[t + 128] = f2b(d1 * rstd * g[t + 128] + bta[t + 128]);
    q[t + 256] = f2b(d2 * rstd * g[t + 256] + bta[t + 256]);
}

// ---------- MFMA GEMM: C[M,N] = act(A[M,K]bf16 @ W[N,K]^T bf16 + bias) (+res) ----------
// BM=64 BN=64 BK=64, 4 waves (2x2) each 32x32 via 2x2x(2 ks) 16x16x32 MFMAs.
// 2-stage register prefetch: load tile k+1 to regs while computing tile k from LDS.
// Requires: M % 64 == 0 (true for all call sites), N % 64 == 0, K % 64 == 0.
template <typename TC>
__global__ __launch_bounds__(256) void mf_gemm(const bf16* __restrict__ A, const bf16* __restrict__ W,
                                               const float* __restrict__ bias, const float* __restrict__ res,
                                               TC* __restrict__ C, int M, int N, int K, int act) {
    __shared__ bf16 As[64][72];
    __shared__ bf16 Ws[64][72];
    int t = threadIdx.x;
    int m0 = blockIdx.y * 64, n0 = blockIdx.x * 64;
    int lane = t & 63, wv = t >> 6;
    int wm = (wv >> 1) * 32, wn = (wv & 1) * 32;
    int fr = lane & 15, fq = lane >> 4;
    int sr = t >> 2, sc = (t & 3) * 16;   // staging: 4 thr/row, 32B (2 x uint4) each
    const bf16* pa = A + (size_t)(m0 + sr) * K + sc;
    const bf16* pw = W + (size_t)(n0 + sr) * K + sc;
    uint4 ra0 = *(const uint4*)pa;
    uint4 ra1 = *(const uint4*)(pa + 8);
    uint4 rw0 = *(const uint4*)pw;
    uint4 rw1 = *(const uint4*)(pw + 8);
    f32x4 acc[2][2] = {};
    int k0 = 0;
    for (;;) {
        *(uint4*)&As[sr][sc] = ra0; *(uint4*)&As[sr][sc + 8] = ra1;
        *(uint4*)&Ws[sr][sc] = rw0; *(uint4*)&Ws[sr][sc + 8] = rw1;
        __syncthreads();
        k0 += 64;
        bool more = (k0 < K);
        if (more) {
            ra0 = *(const uint4*)(pa + k0); ra1 = *(const uint4*)(pa + k0 + 8);
            rw0 = *(const uint4*)(pw + k0); rw1 = *(const uint4*)(pw + k0 + 8);
        }
#pragma unroll
        for (int ks = 0; ks < 2; ++ks) {
            short8 a0 = *(const short8*)&As[wm + fr][ks * 32 + fq * 8];
            short8 a1 = *(const short8*)&As[wm + 16 + fr][ks * 32 + fq * 8];
            short8 b0 = *(const short8*)&Ws[wn + fr][ks * 32 + fq * 8];
            short8 b1 = *(const short8*)&Ws[wn + 16 + fr][ks * 32 + fq * 8];
            acc[0][0] = __builtin_amdgcn_mfma_f32_16x16x32_bf16(a0, b0, acc[0][0], 0, 0, 0);
            acc[0][1] = __builtin_amdgcn_mfma_f32_16x16x32_bf16(a0, b1, acc[0][1], 0, 0, 0);
            acc[1][0] = __builtin_amdgcn_mfma_f32_16x16x32_bf16(a1, b0, acc[1][0], 0, 0, 0);
            acc[1][1] = __builtin_amdgcn_mfma_f32_16x16x32_bf16(a1, b1, acc[1][1], 0, 0, 0);
        }
        if (!more) break;
        __syncthreads();
    }
#pragma unroll
    for (int i = 0; i < 2; ++i) {
#pragma unroll
        for (int r = 0; r < 4; ++r) {
            int row = m0 + wm + i * 16 + fq * 4 + r;
            size_t ro = (size_t)row * N;
#pragma unroll
            for (int j = 0; j < 2; ++j) {
                int col = n0 + wn + j * 16 + fr;
                float c = acc[i][j][r];
                if (bias) c += bias[col];
                if (act == 1) c = gelu(c);
                if (res) c += res[ro + col];
                stc(&C[ro + col], c);
            }
        }
    }
}

// ---------- fused N=16 adapter: one WAVE per row, no barriers/LDS ----------
// mode 0: dst[row] += 0.7*(gelu(xfn[row]@dw^T+db)@uw^T+ub) + xfn[row]     rows = M1
// mode 1: row->(b,no); src = no==0 ? xc[b*NT] : xp[b*128+no-1];
//         dst[row] = gelu(src@dw^T+db)@uw^T+ub + src                      rows = BB*129
__global__ __launch_bounds__(256) void k_adapter(const float* __restrict__ xfn, const float* __restrict__ xc,
                                                 const float* __restrict__ dw, const float* __restrict__ db,
                                                 const float* __restrict__ uw, const float* __restrict__ ub,
                                                 float* __restrict__ dst, int mode) {
    int t = threadIdx.x;
    int lane = t & 63;
    int row = blockIdx.x * 4 + (t >> 6);
    const float* s;
    float* d;
    if (mode == 0) {
        s = xfn + (size_t)row * DD;
        d = dst + (size_t)row * DD;
    } else {
        int b = row / 129, no = row % 129;
        s = (no == 0) ? xc + (size_t)(b * NT) * DD
                      : xfn + (size_t)(b * 128 + no - 1) * DD;
        d = dst + (size_t)row * DD;
    }
    // down: lane = (g 0..15, seg 0..3); partial dot over 96 elems, fold across segs
    int g = lane & 15, seg = lane >> 4;
    const float* wg = dw + g * DD + seg * 96;
    const float* sg = s + seg * 96;
    float part = 0.f;
#pragma unroll
    for (int j = 0; j < 24; ++j) {
        float4 a = *(const float4*)(sg + j * 4);
        float4 w = *(const float4*)(wg + j * 4);
        part += a.x * w.x + a.y * w.y + a.z * w.z + a.w * w.w;
    }
    part += __shfl_xor(part, 16, 64);
    part += __shfl_xor(part, 32, 64);
    float tg = gelu(part + db[g]);   // every lane holds full dot for its g = lane&15
    float tl[16];
#pragma unroll
    for (int c = 0; c < 16; ++c) tl[c] = __shfl(tg, c, 64);
    // up: 6 output elems per lane
#pragma unroll
    for (int k = 0; k < 6; ++k) {
        int dd = lane + k * 64;
        float acc = 0.f;
#pragma unroll
        for (int c = 0; c < 4; ++c) {
            float4 u = *(const float4*)(uw + dd * 16 + c * 4);
            acc += tl[c * 4 + 0] * u.x + tl[c * 4 + 1] * u.y
                 + tl[c * 4 + 2] * u.z + tl[c * 4 + 3] * u.w;
        }
        acc += ub[dd];
        if (mode == 0) d[dd] += 0.7f * acc + s[dd];
        else           d[dd] = acc + s[dd];
    }
}

// ---------- stage-1 attention (MFMA): one block per (b,h) ----------
__global__ __launch_bounds__(256) void k_attn1(const bf16* __restrict__ qkv, bf16* __restrict__ o_out,
                                               float* __restrict__ attn_out) {
    int bh = blockIdx.x;
    int b = bh / HH, h = bh % HH;
    __shared__ unsigned short Kl[144][72];
    __shared__ unsigned short Vt[64][160];
    __shared__ unsigned short Pl[4][16][160];
    int t = threadIdx.x;
    int lane = t & 63, wv = t >> 6;
    int fr = lane & 15, fq = lane >> 4;
    const unsigned short* q16 = (const unsigned short*)qkv;
    size_t base = (size_t)b * NT * 1152;

    uint4 z4 = make_uint4(0, 0, 0, 0);
    for (int i = t * 8; i < 64 * 160; i += 2048) *(uint4*)(&Vt[0][0] + i) = z4;
    for (int i = t * 8; i < 4 * 16 * 160; i += 2048) *(uint4*)(&Pl[0][0][0] + i) = z4;
    for (int i = t; i < 144 * 8; i += 256) {
        int row = i >> 3, ch = (i & 7) * 8;
        uint4 v = z4;
        if (row < NT) v = *(const uint4*)(q16 + base + row * 1152 + 384 + h * 64 + ch);
        *(uint4*)&Kl[row][ch] = v;
    }
    for (int i = t; i < NT * 16; i += 256) {
        int m = i >> 4, dq = (i & 15) * 4;
        ushort4 v = *(const ushort4*)(q16 + base + m * 1152 + 768 + h * 64 + dq);
        Vt[dq + 0][m] = v.x; Vt[dq + 1][m] = v.y;
        Vt[dq + 2][m] = v.z; Vt[dq + 3][m] = v.w;
    }
    __syncthreads();

    for (int nt = wv; nt < 9; nt += 4) {
        int n0 = nt * 16;
        int arow = n0 + fr; if (arow > NT - 1) arow = NT - 1;
        const unsigned short* qp = q16 + base + (size_t)arow * 1152 + h * 64 + fq * 8;
        short8 a0 = *(const short8*)qp;
        short8 a1 = *(const short8*)(qp + 32);
        f32x4 s[9] = {};
#pragma unroll
        for (int mt = 0; mt < 9; ++mt) {
            short8 b0 = *(const short8*)&Kl[mt * 16 + fr][fq * 8];
            short8 b1 = *(const short8*)&Kl[mt * 16 + fr][32 + fq * 8];
            s[mt] = __builtin_amdgcn_mfma_f32_16x16x32_bf16(a0, b0, s[mt], 0, 0, 0);
            s[mt] = __builtin_amdgcn_mfma_f32_16x16x32_bf16(a1, b1, s[mt], 0, 0, 0);
        }
#pragma unroll
        for (int r = 0; r < 4; ++r) {
            float e[9];
            float mx = -1e30f;
#pragma unroll
            for (int mt = 0; mt < 9; ++mt) {
                int col = mt * 16 + fr;
                float v = (col < NT) ? s[mt][r] * SCALE : -1e30f;
                e[mt] = v;
                mx = fmaxf(mx, v);
            }
#pragma unroll
            for (int off = 1; off < 16; off <<= 1) mx = fmaxf(mx, __shfl_xor(mx, off, 64));
            float sm = 0.f;
#pragma unroll
            for (int mt = 0; mt < 9; ++mt) { e[mt] = __expf(e[mt] - mx); sm += e[mt]; }
#pragma unroll
            for (int off = 1; off < 16; off <<= 1) sm += __shfl_xor(sm, off, 64);
            float inv = 1.0f / sm;
            int n = n0 + fq * 4 + r;
            bool nv = n < NT;
            size_t ab = ((size_t)(b * HH + h) * NT + n) * NT;
#pragma unroll
            for (int mt = 0; mt < 9; ++mt) {
                float p = e[mt] * inv;
                int col = mt * 16 + fr;
                if (nv && col < NT) attn_out[ab + col] = p;
                Pl[wv][fq * 4 + r][col] = f2bu(p);
            }
        }
        __syncthreads();
        f32x4 oac[4] = {};
#pragma unroll
        for (int ks = 0; ks < 5; ++ks) {
            short8 ap = *(const short8*)&Pl[wv][fr][ks * 32 + fq * 8];
#pragma unroll
            for (int dt = 0; dt < 4; ++dt) {
                short8 bv = *(const short8*)&Vt[dt * 16 + fr][ks * 32 + fq * 8];
                oac[dt] = __builtin_amdgcn_mfma_f32_16x16x32_bf16(ap, bv, oac[dt], 0, 0, 0);
            }
        }
#pragma unroll
        for (int dt = 0; dt < 4; ++dt)
#pragma unroll
            for (int r = 0; r < 4; ++r) {
                int n = n0 + fq * 4 + r;
                if (n < NT)
                    o_out[((size_t)(b * NT + n)) * DD + h * 64 + dt * 16 + fr] = f2b(oac[dt][r]);
            }
    }
}

// ---------- stage-2 per-group attention (MFMA): one wave per group ----------
__global__ __launch_bounds__(64) void k_attn2(const bf16* __restrict__ qkv, const int* __restrict__ idx,
                                              bf16* __restrict__ o1) {
    int g = blockIdx.x;
    __shared__ unsigned short Vt2[64][40];
    __shared__ unsigned short P2[16][40];
    __shared__ int ridx[16];
    int t = threadIdx.x;
    int fr = t & 15, fq = t >> 4;
    const unsigned short* q16 = (const unsigned short*)qkv;
    if (t < 16) ridx[t] = idx[g * 16 + t];
    uint4 z4 = make_uint4(0, 0, 0, 0);
    for (int i = t * 8; i < 64 * 40; i += 512) *(uint4*)(&Vt2[0][0] + i) = z4;
    for (int i = t * 8; i < 16 * 40; i += 512) *(uint4*)(&P2[0][0] + i) = z4;
    __syncthreads();
    size_t qb = (size_t)ridx[fr] * 1152;
    for (int h = 0; h < HH; ++h) {
        for (int i = t; i < 256; i += 64) {
            int m = i >> 4, dq = (i & 15) * 4;
            ushort4 v = *(const ushort4*)(q16 + (size_t)ridx[m] * 1152 + 768 + h * 64 + dq);
            Vt2[dq + 0][m] = v.x; Vt2[dq + 1][m] = v.y;
            Vt2[dq + 2][m] = v.z; Vt2[dq + 3][m] = v.w;
        }
        __syncthreads();
        const unsigned short* qp = q16 + qb + h * 64 + fq * 8;
        const unsigned short* kp = q16 + qb + 384 + h * 64 + fq * 8;
        short8 a0 = *(const short8*)qp;
        short8 a1 = *(const short8*)(qp + 32);
        short8 b0 = *(const short8*)kp;
        short8 b1 = *(const short8*)(kp + 32);
        f32x4 s = {};
        s = __builtin_amdgcn_mfma_f32_16x16x32_bf16(a0, b0, s, 0, 0, 0);
        s = __builtin_amdgcn_mfma_f32_16x16x32_bf16(a1, b1, s, 0, 0, 0);
#pragma unroll
        for (int r = 0; r < 4; ++r) {
            float v = s[r] * SCALE;
            float mx = v;
#pragma unroll
            for (int off = 1; off < 16; off <<= 1) mx = fmaxf(mx, __shfl_xor(mx, off, 64));
            float e = __expf(v - mx), sm = e;
#pragma unroll
            for (int off = 1; off < 16; off <<= 1) sm += __shfl_xor(sm, off, 64);
            P2[fq * 4 + r][fr] = f2bu(e / sm);
        }
        __syncthreads();
        short8 ap = *(const short8*)&P2[fr][fq * 8];
        f32x4 oac[4] = {};
#pragma unroll
        for (int dt = 0; dt < 4; ++dt) {
            short8 bv = *(const short8*)&Vt2[dt * 16 + fr][fq * 8];
            oac[dt] = __builtin_amdgcn_mfma_f32_16x16x32_bf16(ap, bv, oac[dt], 0, 0, 0);
        }
#pragma unroll
        for (int dt = 0; dt < 4; ++dt)
#pragma unroll
            for (int r = 0; r < 4; ++r)
                o1[((size_t)(g * 16 + fq * 4 + r)) * DD + h * 64 + dt * 16 + fr] = f2b(oac[dt][r]);
        __syncthreads();
    }
}

// ---------- group residual + max + BN + GELU + centers -> vis ----------
__global__ __launch_bounds__(128) void k_groupmax(const bf16* __restrict__ att, const float* __restrict__ xc,
                                                  const int* __restrict__ idx, const int* __restrict__ cidx,
                                                  const float* __restrict__ bg, const float* __restrict__ bb,
                                                  const float* __restrict__ bmean, const float* __restrict__ bvar,
                                                  float* __restrict__ vis) {
    int g = blockIdx.x, t = threadIdx.x;
    __shared__ int rows[16];
    __shared__ int crow;
    if (t < 16) { int r = idx[g * 16 + t]; rows[t] = (r / GG) * NT + 1 + (r % GG); }
    if (t == 16) { int r = cidx[g]; crow = (r / GG) * NT + 1 + (r % GG); }
    __syncthreads();
    for (int d = t; d < DD; d += 128) {
        float m = -INFINITY;
#pragma unroll
        for (int j = 0; j < 16; ++j) {
            float v = b2f(att[((size_t)(g * 16 + j)) * DD + d]) + xc[(size_t)rows[j] * DD + d];
            m = fmaxf(m, v);
        }
        float bn = (m - bmean[d]) * rsqrtf(bvar[d] + 1e-5f) * bg[d] + bb[d];
        bn = gelu(bn);
        vis[(size_t)g * DD + d] = bn + 0.3f * xc[(size_t)crow * DD + d];
    }
}

// ---------- propagate ----------
__global__ __launch_bounds__(128) void k_propagate(const float* __restrict__ c1, const float* __restrict__ c2,
                                                   const float* __restrict__ xc, const float* __restrict__ vis,
                                                   float* __restrict__ xp) {
    int blk = blockIdx.x;
    int b = blk >> 7, i = blk & 127;
    int t = threadIdx.x;
    __shared__ float wl[32];
    __shared__ float wsum;
    if (t < 32) {
        float dx = c1[(b * 128 + i) * 3 + 0] - c2[(b * 32 + t) * 3 + 0];
        float dy = c1[(b * 128 + i) * 3 + 1] - c2[(b * 32 + t) * 3 + 1];
        float dz = c1[(b * 128 + i) * 3 + 2] - c2[(b * 32 + t) * 3 + 2];
        wl[t] = 1.0f / (dx * dx + dy * dy + dz * dz + 1e-8f);
    }
    __syncthreads();
    if (t == 0) {
        float s = 0.f;
        for (int j = 0; j < 32; ++j) s += wl[j];
        wsum = s;
    }
    __syncthreads();
    float sc = 0.3f / wsum;
    for (int d = t; d < DD; d += 128) {
        float acc = 0.f;
#pragma unroll 8
        for (int j = 0; j < 32; ++j) acc += wl[j] * vis[((size_t)(b * 32 + j)) * DD + d];
        xp[((size_t)(b * 128 + i)) * DD + d] = xc[((size_t)(b * NT + 11 + i)) * DD + d] + sc * acc;
    }
}

extern "C" void kernel_launch(void* const* d_in, const int* in_sizes, int n_in,
                              void* d_out, int out_size, void* d_ws, size_t ws_size,
                              hipStream_t stream) {
    const float* x_in    = (const float*)d_in[0];
    const float* center1 = (const float*)d_in[2];
    const float* center2 = (const float*)d_in[3];
    const int*   idx     = (const int*)d_in[5];
    const int*   cidx    = (const int*)d_in[6];
    const float* ln1_g   = (const float*)d_in[9];
    const float* ln1_b   = (const float*)d_in[10];
    const float* ln2_g   = (const float*)d_in[11];
    const float* ln2_b   = (const float*)d_in[12];
    const float* qkv_w   = (const float*)d_in[13];
    const float* proj_w  = (const float*)d_in[14];
    const float* proj_b  = (const float*)d_in[15];
    const float* fc1_w   = (const float*)d_in[16];
    const float* fc1_b   = (const float*)d_in[17];
    const float* fc2_w   = (const float*)d_in[18];
    const float* fc2_b   = (const float*)d_in[19];
    const float* ad_dw   = (const float*)d_in[20];
    const float* ad_db   = (const float*)d_in[21];
    const float* ad_uw   = (const float*)d_in[22];
    const float* ad_ub   = (const float*)d_in[23];
    const float* ad1_dw  = (const float*)d_in[24];
    const float* ad1_db  = (const float*)d_in[25];
    const float* ad1_uw  = (const float*)d_in[26];
    const float* ad1_ub  = (const float*)d_in[27];
    const float* prompt  = (const float*)d_in[28];
    const float* bn_g    = (const float*)d_in[29];
    const float* bn_b    = (const float*)d_in[30];
    const float* bn_mean = (const float*)d_in[31];
    const float* bn_var  = (const float*)d_in[32];
    const float* qkv1_w  = (const float*)d_in[33];
    const float* proj1_w = (const float*)d_in[34];
    const float* proj1_b = (const float*)d_in[35];
    const float* ln3_g   = (const float*)d_in[36];
    const float* ln3_b   = (const float*)d_in[37];

    char* wsb = (char*)d_ws;
    float* XC   = (float*)(wsb + XC_OFF);
    float* VIS  = (float*)(wsb + VIS_OFF);
    bf16*  XNB  = (bf16*)(wsb + XNB_OFF);
    float* XFN  = (float*)(wsb + XFN_OFF);
    bf16*  BIG1 = (bf16*)(wsb + BIG1_OFF);
    bf16*  BIG2 = (bf16*)(wsb + BIG2_OFF);
    bf16*  ATT  = (bf16*)(wsb + ATT_OFF);
    bf16*  WB   = (bf16*)(wsb + WB_OFF);

    float* out_x    = (float*)d_out;
    float* out_attn = out_x + OUT_X;

    // --- weights -> bf16 (graph-safe: every call) ---
    k_wconv<<<(WB_TOTAL / 4 + 255) / 256, 256, 0, stream>>>(qkv_w, proj_w, fc1_w, fc2_w, qkv1_w, proj1_w, WB);

    // --- stage 1 ---
    k_build_ln<<<M1, 128, 0, stream>>>(x_in, prompt, ln1_g, ln1_b, XC, XNB);
    mf_gemm<<<dim3(18, 139), 256, 0, stream>>>(XNB, WB + WB_QKV, (const float*)nullptr, (const float*)nullptr, BIG1, M1, 1152, 384, 0);
    k_attn1<<<BB * HH, 256, 0, stream>>>(BIG1, XNB, out_attn);
    mf_gemm<<<dim3(6, 139), 256, 0, stream>>>(XNB, WB + WB_PROJ, proj_b, XC, XC, M1, 384, 384, 0);
    k_layernorm<<<M1, 128, 0, stream>>>(XC, XNB, ln2_g, ln2_b, 0);
    mf_gemm<<<dim3(24, 139), 256, 0, stream>>>(XNB, WB + WB_FC1, fc1_b, (const float*)nullptr, BIG2, M1, 1536, 384, 1);
    mf_gemm<<<dim3(6, 139), 256, 0, stream>>>(BIG2, WB + WB_FC2, fc2_b, (const float*)nullptr, XFN, M1, 384, 1536, 0);
    k_adapter<<<M1 / 4, 256, 0, stream>>>(XFN, XC, ad_dw, ad_db, ad_uw, ad_ub, XC, 0);

    // --- stage 2 (group attention on 8832 unique rows) ---
    k_layernorm<<<MG, 128, 0, stream>>>(XC, XNB, ln3_g, ln3_b, 1);
    mf_gemm<<<dim3(18, 138), 256, 0, stream>>>(XNB, WB + WB_QKV1, (const float*)nullptr, (const float*)nullptr, BIG1, MG, 1152, 384, 0);
    k_attn2<<<NGRP, 64, 0, stream>>>(BIG1, idx, BIG2);
    mf_gemm<<<dim3(6, 512), 256, 0, stream>>>(BIG2, WB + WB_PROJ1, proj1_b, (const float*)nullptr, ATT, NGRP * 16, 384, 384, 0);
    k_groupmax<<<NGRP, 128, 0, stream>>>(ATT, XC, idx, cidx, bn_g, bn_b, bn_mean, bn_var, VIS);
    k_propagate<<<BB * 128, 128, 0, stream>>>(center1, center2, XC, VIS, XFN);

    // --- final adapter (reads xc/xp directly; x_final never materialized) ---
    k_adapter<<<BB * 129 / 4, 256, 0, stream>>>(XFN, XC, ad1_dw, ad1_db, ad1_uw, ad1_ub, out_x, 1);
}

// Round 6
// 487.191 us; speedup vs baseline: 1.6210x; 1.0084x over previous
//
#include <hip/hip_runtime.h>
#include <hip/hip_bf16.h>

typedef __hip_bfloat16 bf16;
typedef __attribute__((ext_vector_type(8))) short short8;
typedef __attribute__((ext_vector_type(4))) float f32x4;

#define DEV static __device__ __forceinline__

DEV float b2f(bf16 v) { return __bfloat162float(v); }
DEV bf16 f2b(float v) { return __float2bfloat16(v); }
DEV unsigned short f2bu(float v) { return __builtin_bit_cast(unsigned short, __float2bfloat16(v)); }
DEV float u2f(unsigned short u) { return __uint_as_float(((unsigned int)u) << 16); }
DEV float gelu(float x) { return 0.5f * x * (1.0f + erff(x * 0.70710678118654752f)); }

// Problem constants
#define BB 64
#define NT 139     // 1 + T + G1
#define DD 384
#define TT 10
#define HH 6
#define GG 138     // G1 + T
#define M1 8896    // BB*NT = 64*139, multiple of 64
#define MG 8832    // BB*GG = 64*138, multiple of 64
#define NGRP 2048  // BB*S
#define SCALE 0.125f

// Workspace byte offsets (proven layout; + bf16 weights block = 90.4 MB)
#define XC_OFF   0UL          // f32 8896x384 residual stream, live whole call
#define VIS_OFF  13664256UL   // f32 2048x384
#define XNB_OFF  16809984UL   // bf16 8896x384: LN out; attn1 o; dead after consumer
#define XFN_OFF  23642112UL   // f32 8896x384: fc2 out; x_prop
#define BIG1_OFF 37875712UL   // bf16 8896x1152: qkv / qkv1
#define BIG2_OFF 58372096UL   // bf16 8896x1536 fc1h / bf16 32768x384 o1
#define ATT_OFF  XNB_OFF      // bf16 32768x384 proj1 out (overlays dead XNB..BIG1 prefix)
#define WB_OFF   85700608UL   // bf16 2359296: pre-converted weights

// bf16 weight block element offsets
#define WB_QKV   0
#define WB_PROJ  442368
#define WB_FC1   589824
#define WB_FC2   1179648
#define WB_QKV1  1769472
#define WB_PROJ1 2211840
#define WB_TOTAL 2359296

#define OUT_X 3170304  // 64*129*384

DEV float4 ld4(const float* p) { return *(const float4*)p; }
DEV float4 ld4(const bf16* p) {
    ushort4 u = *(const ushort4*)p;
    return make_float4(u2f(u.x), u2f(u.y), u2f(u.z), u2f(u.w));
}
DEV void stc(float* p, float v) { *p = v; }
DEV void stc(bf16* p, float v) { *p = f2b(v); }

// ---------- weights f32 -> bf16 (once per call) ----------
__global__ __launch_bounds__(256) void k_wconv(const float* __restrict__ w0, const float* __restrict__ w1,
                                               const float* __restrict__ w2, const float* __restrict__ w3,
                                               const float* __restrict__ w4, const float* __restrict__ w5,
                                               bf16* __restrict__ dst) {
    int i4 = (blockIdx.x * 256 + threadIdx.x) * 4;
    if (i4 >= WB_TOTAL) return;
    const float* s; int off;
    if (i4 < WB_PROJ)       { s = w0; off = WB_QKV; }
    else if (i4 < WB_FC1)   { s = w1; off = WB_PROJ; }
    else if (i4 < WB_FC2)   { s = w2; off = WB_FC1; }
    else if (i4 < WB_QKV1)  { s = w3; off = WB_FC2; }
    else if (i4 < WB_PROJ1) { s = w4; off = WB_QKV1; }
    else                    { s = w5; off = WB_PROJ1; }
    float4 v = *(const float4*)(s + (i4 - off));
    ushort4 u;
    u.x = f2bu(v.x); u.y = f2bu(v.y); u.z = f2bu(v.z); u.w = f2bu(v.w);
    *(ushort4*)((unsigned short*)dst + i4) = u;
}

// ---------- fused concat + LN1: xc row built AND layernormed -> xnb (one pass) ----------
__global__ __launch_bounds__(128) void k_build_ln(const float* __restrict__ x, const float* __restrict__ pe,
                                                  const float* __restrict__ g, const float* __restrict__ bta,
                                                  float* __restrict__ xc, bf16* __restrict__ dst) {
    int r = blockIdx.x;
    int n = r % NT, b = r / NT;
    const float* p;
    if (n == 0)       p = x + (size_t)(b * 129) * DD;
    else if (n <= TT) p = pe + (size_t)(n - 1) * DD;
    else              p = x + (size_t)(b * 129 + n - TT) * DD;
    int t = threadIdx.x;
    float v0 = p[t], v1 = p[t + 128], v2 = p[t + 256];
    float* xr = xc + (size_t)r * DD;
    xr[t] = v0; xr[t + 128] = v1; xr[t + 256] = v2;
    __shared__ float red[4];
    float s = v0 + v1 + v2;
    for (int off = 32; off; off >>= 1) s += __shfl_down(s, off, 64);
    if ((t & 63) == 0) red[t >> 6] = s;
    __syncthreads();
    float mean = (red[0] + red[1]) * (1.0f / 384.0f);
    float d0 = v0 - mean, d1 = v1 - mean, d2 = v2 - mean;
    float s2 = d0 * d0 + d1 * d1 + d2 * d2;
    for (int off = 32; off; off >>= 1) s2 += __shfl_down(s2, off, 64);
    if ((t & 63) == 0) red[2 + (t >> 6)] = s2;
    __syncthreads();
    float rstd = rsqrtf((red[2] + red[3]) * (1.0f / 384.0f) + 1e-5f);
    bf16* q = dst + (size_t)r * DD;
    q[t]       = f2b(d0 * rstd * g[t]       + bta[t]);
    q[t + 128] = f2b(d1 * rstd * g[t + 128] + bta[t + 128]);
    q[t + 256] = f2b(d2 * rstd * g[t + 256] + bta[t + 256]);
}

// ---------- layernorm f32 -> bf16 (mode 1: gather row (r/138)*139+1+(r%138)) ----------
__global__ __launch_bounds__(128) void k_layernorm(const float* __restrict__ src, bf16* __restrict__ dst,
                                                   const float* __restrict__ g, const float* __restrict__ bta,
                                                   int mode) {
    int r = blockIdx.x;
    int srow = r;
    if (mode) srow = (r / GG) * NT + 1 + (r % GG);
    const float* p = src + (size_t)srow * DD;
    int t = threadIdx.x;
    float v0 = p[t], v1 = p[t + 128], v2 = p[t + 256];
    __shared__ float red[4];
    float s = v0 + v1 + v2;
    for (int off = 32; off; off >>= 1) s += __shfl_down(s, off, 64);
    if ((t & 63) == 0) red[t >> 6] = s;
    __syncthreads();
    float mean = (red[0] + red[1]) * (1.0f / 384.0f);
    float d0 = v0 - mean, d1 = v1 - mean, d2 = v2 - mean;
    float s2 = d0 * d0 + d1 * d1 + d2 * d2;
    for (int off = 32; off; off >>= 1) s2 += __shfl_down(s2, off, 64);
    if ((t & 63) == 0) red[2 + (t >> 6)] = s2;
    __syncthreads();
    float rstd = rsqrtf((red[2] + red[3]) * (1.0f / 384.0f) + 1e-5f);
    bf16* q = dst + (size_t)r * DD;
    q[t]       = f2b(d0 * rstd * g[t]       + bta[t]);
    q[t + 128] = f2b(d1 * rstd * g[t + 128] + bta[t + 128]);
    q[t + 256] = f2b(d2 * rstd * g[t + 256] + bta[t + 256]);
}

// ---------- MFMA GEMM: C[M,N] = act(A[M,K]bf16 @ W[N,K]^T bf16 + bias) (+res) ----------
// BM=64 BN=64 BK=64, 4 waves (2x2) each 32x32 via 2x2x(2 ks) 16x16x32 MFMAs.
// 2-stage register prefetch: load tile k+1 to regs while computing tile k from LDS.
// Requires: M % 64 == 0 (true for all call sites), N % 64 == 0, K % 64 == 0.
template <typename TC>
__global__ __launch_bounds__(256) void mf_gemm(const bf16* __restrict__ A, const bf16* __restrict__ W,
                                               const float* __restrict__ bias, const float* __restrict__ res,
                                               TC* __restrict__ C, int M, int N, int K, int act) {
    __shared__ bf16 As[64][72];
    __shared__ bf16 Ws[64][72];
    int t = threadIdx.x;
    int m0 = blockIdx.y * 64, n0 = blockIdx.x * 64;
    int lane = t & 63, wv = t >> 6;
    int wm = (wv >> 1) * 32, wn = (wv & 1) * 32;
    int fr = lane & 15, fq = lane >> 4;
    int sr = t >> 2, sc = (t & 3) * 16;   // staging: 4 thr/row, 32B (2 x uint4) each
    const bf16* pa = A + (size_t)(m0 + sr) * K + sc;
    const bf16* pw = W + (size_t)(n0 + sr) * K + sc;
    uint4 ra0 = *(const uint4*)pa;
    uint4 ra1 = *(const uint4*)(pa + 8);
    uint4 rw0 = *(const uint4*)pw;
    uint4 rw1 = *(const uint4*)(pw + 8);
    f32x4 acc[2][2] = {};
    int k0 = 0;
    for (;;) {
        *(uint4*)&As[sr][sc] = ra0; *(uint4*)&As[sr][sc + 8] = ra1;
        *(uint4*)&Ws[sr][sc] = rw0; *(uint4*)&Ws[sr][sc + 8] = rw1;
        __syncthreads();
        k0 += 64;
        bool more = (k0 < K);
        if (more) {
            ra0 = *(const uint4*)(pa + k0); ra1 = *(const uint4*)(pa + k0 + 8);
            rw0 = *(const uint4*)(pw + k0); rw1 = *(const uint4*)(pw + k0 + 8);
        }
#pragma unroll
        for (int ks = 0; ks < 2; ++ks) {
            short8 a0 = *(const short8*)&As[wm + fr][ks * 32 + fq * 8];
            short8 a1 = *(const short8*)&As[wm + 16 + fr][ks * 32 + fq * 8];
            short8 b0 = *(const short8*)&Ws[wn + fr][ks * 32 + fq * 8];
            short8 b1 = *(const short8*)&Ws[wn + 16 + fr][ks * 32 + fq * 8];
            acc[0][0] = __builtin_amdgcn_mfma_f32_16x16x32_bf16(a0, b0, acc[0][0], 0, 0, 0);
            acc[0][1] = __builtin_amdgcn_mfma_f32_16x16x32_bf16(a0, b1, acc[0][1], 0, 0, 0);
            acc[1][0] = __builtin_amdgcn_mfma_f32_16x16x32_bf16(a1, b0, acc[1][0], 0, 0, 0);
            acc[1][1] = __builtin_amdgcn_mfma_f32_16x16x32_bf16(a1, b1, acc[1][1], 0, 0, 0);
        }
        if (!more) break;
        __syncthreads();
    }
#pragma unroll
    for (int i = 0; i < 2; ++i) {
#pragma unroll
        for (int r = 0; r < 4; ++r) {
            int row = m0 + wm + i * 16 + fq * 4 + r;
            size_t ro = (size_t)row * N;
#pragma unroll
            for (int j = 0; j < 2; ++j) {
                int col = n0 + wn + j * 16 + fr;
                float c = acc[i][j][r];
                if (bias) c += bias[col];
                if (act == 1) c = gelu(c);
                if (res) c += res[ro + col];
                stc(&C[ro + col], c);
            }
        }
    }
}

// ---------- fused N=16 adapter: 4 rows/block, LDS-staged rows (MLP via coalesced staging) ----------
// mode 0: dst[row] += 0.7*(gelu(row@dw^T+db)@uw^T+ub) + row       rows = M1, row src = xfn
// mode 1: row->(b,no); src = no==0 ? xc[b*NT] : xp[b*128+no-1];
//         dst[row] = gelu(src@dw^T+db)@uw^T+ub + src               rows = BB*129
DEV const float* adapter_src(const float* xfn, const float* xc, int row, int mode) {
    if (mode == 0) return xfn + (size_t)row * DD;
    int b = row / 129, no = row % 129;
    return (no == 0) ? xc + (size_t)(b * NT) * DD
                     : xfn + (size_t)(b * 128 + no - 1) * DD;
}
__global__ __launch_bounds__(256) void k_adapter(const float* __restrict__ xfn, const float* __restrict__ xc,
                                                 const float* __restrict__ dw, const float* __restrict__ db,
                                                 const float* __restrict__ uw, const float* __restrict__ ub,
                                                 float* __restrict__ dst, int mode) {
    __shared__ float S[4][DD];
    int t = threadIdx.x;
    int lane = t & 63, wv = t >> 6;
    int row0 = blockIdx.x * 4;
    // Stage 4 rows (4 x 96 float4) with coalesced, independent loads: max MLP per block.
#pragma unroll
    for (int i = 0; i < 2; ++i) {
        int F = t + i * 256;
        if (F < 384) {
            int r = F / 96, c = F - r * 96;
            const float* sp = adapter_src(xfn, xc, row0 + r, mode);
            *(float4*)&S[r][c * 4] = *(const float4*)(sp + c * 4);
        }
    }
    __syncthreads();
    const float* srow = S[wv];
    int row = row0 + wv;
    float* d = dst + (size_t)row * DD;
    // down: lane = (g 0..15, seg 0..3); dot over this seg's 96 elems from LDS.
    // seg-rotated j order avoids the 4-way bank alias of the 384B seg stride.
    int g = lane & 15, seg = lane >> 4;
    const float* wg = dw + g * DD + seg * 96;
    const float* sg = srow + seg * 96;
    float part = 0.f;
#pragma unroll
    for (int j = 0; j < 24; ++j) {
        int jj = j + seg * 6; if (jj >= 24) jj -= 24;
        float4 a = *(const float4*)(sg + jj * 4);
        float4 w = *(const float4*)(wg + jj * 4);
        part += a.x * w.x + a.y * w.y + a.z * w.z + a.w * w.w;
    }
    part += __shfl_xor(part, 16, 64);
    part += __shfl_xor(part, 32, 64);
    float tg = gelu(part + db[g]);   // every lane holds full dot for its g = lane&15
    float tl[16];
#pragma unroll
    for (int c = 0; c < 16; ++c) tl[c] = __shfl(tg, c, 64);
    // up: 6 output elems per lane; residual read from LDS
#pragma unroll
    for (int k = 0; k < 6; ++k) {
        int dd = lane + k * 64;
        float acc = 0.f;
#pragma unroll
        for (int c = 0; c < 4; ++c) {
            float4 u = *(const float4*)(uw + dd * 16 + c * 4);
            acc += tl[c * 4 + 0] * u.x + tl[c * 4 + 1] * u.y
                 + tl[c * 4 + 2] * u.z + tl[c * 4 + 3] * u.w;
        }
        acc += ub[dd];
        if (mode == 0) d[dd] += 0.7f * acc + srow[dd];
        else           d[dd] = acc + srow[dd];
    }
}

// ---------- stage-1 attention (MFMA): one block per (b,h) ----------
__global__ __launch_bounds__(256) void k_attn1(const bf16* __restrict__ qkv, bf16* __restrict__ o_out,
                                               float* __restrict__ attn_out) {
    int bh = blockIdx.x;
    int b = bh / HH, h = bh % HH;
    __shared__ unsigned short Kl[144][72];
    __shared__ unsigned short Vt[64][160];
    __shared__ unsigned short Pl[4][16][160];
    int t = threadIdx.x;
    int lane = t & 63, wv = t >> 6;
    int fr = lane & 15, fq = lane >> 4;
    const unsigned short* q16 = (const unsigned short*)qkv;
    size_t base = (size_t)b * NT * 1152;

    uint4 z4 = make_uint4(0, 0, 0, 0);
    for (int i = t * 8; i < 64 * 160; i += 2048) *(uint4*)(&Vt[0][0] + i) = z4;
    for (int i = t * 8; i < 4 * 16 * 160; i += 2048) *(uint4*)(&Pl[0][0][0] + i) = z4;
    for (int i = t; i < 144 * 8; i += 256) {
        int row = i >> 3, ch = (i & 7) * 8;
        uint4 v = z4;
        if (row < NT) v = *(const uint4*)(q16 + base + row * 1152 + 384 + h * 64 + ch);
        *(uint4*)&Kl[row][ch] = v;
    }
    for (int i = t; i < NT * 16; i += 256) {
        int m = i >> 4, dq = (i & 15) * 4;
        ushort4 v = *(const ushort4*)(q16 + base + m * 1152 + 768 + h * 64 + dq);
        Vt[dq + 0][m] = v.x; Vt[dq + 1][m] = v.y;
        Vt[dq + 2][m] = v.z; Vt[dq + 3][m] = v.w;
    }
    __syncthreads();

    for (int nt = wv; nt < 9; nt += 4) {
        int n0 = nt * 16;
        int arow = n0 + fr; if (arow > NT - 1) arow = NT - 1;
        const unsigned short* qp = q16 + base + (size_t)arow * 1152 + h * 64 + fq * 8;
        short8 a0 = *(const short8*)qp;
        short8 a1 = *(const short8*)(qp + 32);
        f32x4 s[9] = {};
#pragma unroll
        for (int mt = 0; mt < 9; ++mt) {
            short8 b0 = *(const short8*)&Kl[mt * 16 + fr][fq * 8];
            short8 b1 = *(const short8*)&Kl[mt * 16 + fr][32 + fq * 8];
            s[mt] = __builtin_amdgcn_mfma_f32_16x16x32_bf16(a0, b0, s[mt], 0, 0, 0);
            s[mt] = __builtin_amdgcn_mfma_f32_16x16x32_bf16(a1, b1, s[mt], 0, 0, 0);
        }
#pragma unroll
        for (int r = 0; r < 4; ++r) {
            float e[9];
            float mx = -1e30f;
#pragma unroll
            for (int mt = 0; mt < 9; ++mt) {
                int col = mt * 16 + fr;
                float v = (col < NT) ? s[mt][r] * SCALE : -1e30f;
                e[mt] = v;
                mx = fmaxf(mx, v);
            }
#pragma unroll
            for (int off = 1; off < 16; off <<= 1) mx = fmaxf(mx, __shfl_xor(mx, off, 64));
            float sm = 0.f;
#pragma unroll
            for (int mt = 0; mt < 9; ++mt) { e[mt] = __expf(e[mt] - mx); sm += e[mt]; }
#pragma unroll
            for (int off = 1; off < 16; off <<= 1) sm += __shfl_xor(sm, off, 64);
            float inv = 1.0f / sm;
            int n = n0 + fq * 4 + r;
            bool nv = n < NT;
            size_t ab = ((size_t)(b * HH + h) * NT + n) * NT;
#pragma unroll
            for (int mt = 0; mt < 9; ++mt) {
                float p = e[mt] * inv;
                int col = mt * 16 + fr;
                if (nv && col < NT) attn_out[ab + col] = p;
                Pl[wv][fq * 4 + r][col] = f2bu(p);
            }
        }
        __syncthreads();
        f32x4 oac[4] = {};
#pragma unroll
        for (int ks = 0; ks < 5; ++ks) {
            short8 ap = *(const short8*)&Pl[wv][fr][ks * 32 + fq * 8];
#pragma unroll
            for (int dt = 0; dt < 4; ++dt) {
                short8 bv = *(const short8*)&Vt[dt * 16 + fr][ks * 32 + fq * 8];
                oac[dt] = __builtin_amdgcn_mfma_f32_16x16x32_bf16(ap, bv, oac[dt], 0, 0, 0);
            }
        }
#pragma unroll
        for (int dt = 0; dt < 4; ++dt)
#pragma unroll
            for (int r = 0; r < 4; ++r) {
                int n = n0 + fq * 4 + r;
                if (n < NT)
                    o_out[((size_t)(b * NT + n)) * DD + h * 64 + dt * 16 + fr] = f2b(oac[dt][r]);
            }
    }
}

// ---------- stage-2 per-group attention (MFMA): one wave per group ----------
__global__ __launch_bounds__(64) void k_attn2(const bf16* __restrict__ qkv, const int* __restrict__ idx,
                                              bf16* __restrict__ o1) {
    int g = blockIdx.x;
    __shared__ unsigned short Vt2[64][40];
    __shared__ unsigned short P2[16][40];
    __shared__ int ridx[16];
    int t = threadIdx.x;
    int fr = t & 15, fq = t >> 4;
    const unsigned short* q16 = (const unsigned short*)qkv;
    if (t < 16) ridx[t] = idx[g * 16 + t];
    uint4 z4 = make_uint4(0, 0, 0, 0);
    for (int i = t * 8; i < 64 * 40; i += 512) *(uint4*)(&Vt2[0][0] + i) = z4;
    for (int i = t * 8; i < 16 * 40; i += 512) *(uint4*)(&P2[0][0] + i) = z4;
    __syncthreads();
    size_t qb = (size_t)ridx[fr] * 1152;
    for (int h = 0; h < HH; ++h) {
        for (int i = t; i < 256; i += 64) {
            int m = i >> 4, dq = (i & 15) * 4;
            ushort4 v = *(const ushort4*)(q16 + (size_t)ridx[m] * 1152 + 768 + h * 64 + dq);
            Vt2[dq + 0][m] = v.x; Vt2[dq + 1][m] = v.y;
            Vt2[dq + 2][m] = v.z; Vt2[dq + 3][m] = v.w;
        }
        __syncthreads();
        const unsigned short* qp = q16 + qb + h * 64 + fq * 8;
        const unsigned short* kp = q16 + qb + 384 + h * 64 + fq * 8;
        short8 a0 = *(const short8*)qp;
        short8 a1 = *(const short8*)(qp + 32);
        short8 b0 = *(const short8*)kp;
        short8 b1 = *(const short8*)(kp + 32);
        f32x4 s = {};
        s = __builtin_amdgcn_mfma_f32_16x16x32_bf16(a0, b0, s, 0, 0, 0);
        s = __builtin_amdgcn_mfma_f32_16x16x32_bf16(a1, b1, s, 0, 0, 0);
#pragma unroll
        for (int r = 0; r < 4; ++r) {
            float v = s[r] * SCALE;
            float mx = v;
#pragma unroll
            for (int off = 1; off < 16; off <<= 1) mx = fmaxf(mx, __shfl_xor(mx, off, 64));
            float e = __expf(v - mx), sm = e;
#pragma unroll
            for (int off = 1; off < 16; off <<= 1) sm += __shfl_xor(sm, off, 64);
            P2[fq * 4 + r][fr] = f2bu(e / sm);
        }
        __syncthreads();
        short8 ap = *(const short8*)&P2[fr][fq * 8];
        f32x4 oac[4] = {};
#pragma unroll
        for (int dt = 0; dt < 4; ++dt) {
            short8 bv = *(const short8*)&Vt2[dt * 16 + fr][fq * 8];
            oac[dt] = __builtin_amdgcn_mfma_f32_16x16x32_bf16(ap, bv, oac[dt], 0, 0, 0);
        }
#pragma unroll
        for (int dt = 0; dt < 4; ++dt)
#pragma unroll
            for (int r = 0; r < 4; ++r)
                o1[((size_t)(g * 16 + fq * 4 + r)) * DD + h * 64 + dt * 16 + fr] = f2b(oac[dt][r]);
        __syncthreads();
    }
}

// ---------- group residual + max + BN + GELU + centers -> vis ----------
__global__ __launch_bounds__(128) void k_groupmax(const bf16* __restrict__ att, const float* __restrict__ xc,
                                                  const int* __restrict__ idx, const int* __restrict__ cidx,
                                                  const float* __restrict__ bg, const float* __restrict__ bb,
                                                  const float* __restrict__ bmean, const float* __restrict__ bvar,
                                                  float* __restrict__ vis) {
    int g = blockIdx.x, t = threadIdx.x;
    __shared__ int rows[16];
    __shared__ int crow;
    if (t < 16) { int r = idx[g * 16 + t]; rows[t] = (r / GG) * NT + 1 + (r % GG); }
    if (t == 16) { int r = cidx[g]; crow = (r / GG) * NT + 1 + (r % GG); }
    __syncthreads();
    for (int d = t; d < DD; d += 128) {
        float m = -INFINITY;
#pragma unroll
        for (int j = 0; j < 16; ++j) {
            float v = b2f(att[((size_t)(g * 16 + j)) * DD + d]) + xc[(size_t)rows[j] * DD + d];
            m = fmaxf(m, v);
        }
        float bn = (m - bmean[d]) * rsqrtf(bvar[d] + 1e-5f) * bg[d] + bb[d];
        bn = gelu(bn);
        vis[(size_t)g * DD + d] = bn + 0.3f * xc[(size_t)crow * DD + d];
    }
}

// ---------- propagate ----------
__global__ __launch_bounds__(128) void k_propagate(const float* __restrict__ c1, const float* __restrict__ c2,
                                                   const float* __restrict__ xc, const float* __restrict__ vis,
                                                   float* __restrict__ xp) {
    int blk = blockIdx.x;
    int b = blk >> 7, i = blk & 127;
    int t = threadIdx.x;
    __shared__ float wl[32];
    __shared__ float wsum;
    if (t < 32) {
        float dx = c1[(b * 128 + i) * 3 + 0] - c2[(b * 32 + t) * 3 + 0];
        float dy = c1[(b * 128 + i) * 3 + 1] - c2[(b * 32 + t) * 3 + 1];
        float dz = c1[(b * 128 + i) * 3 + 2] - c2[(b * 32 + t) * 3 + 2];
        wl[t] = 1.0f / (dx * dx + dy * dy + dz * dz + 1e-8f);
    }
    __syncthreads();
    if (t == 0) {
        float s = 0.f;
        for (int j = 0; j < 32; ++j) s += wl[j];
        wsum = s;
    }
    __syncthreads();
    float sc = 0.3f / wsum;
    for (int d = t; d < DD; d += 128) {
        float acc = 0.f;
#pragma unroll 8
        for (int j = 0; j < 32; ++j) acc += wl[j] * vis[((size_t)(b * 32 + j)) * DD + d];
        xp[((size_t)(b * 128 + i)) * DD + d] = xc[((size_t)(b * NT + 11 + i)) * DD + d] + sc * acc;
    }
}

extern "C" void kernel_launch(void* const* d_in, const int* in_sizes, int n_in,
                              void* d_out, int out_size, void* d_ws, size_t ws_size,
                              hipStream_t stream) {
    const float* x_in    = (const float*)d_in[0];
    const float* center1 = (const float*)d_in[2];
    const float* center2 = (const float*)d_in[3];
    const int*   idx     = (const int*)d_in[5];
    const int*   cidx    = (const int*)d_in[6];
    const float* ln1_g   = (const float*)d_in[9];
    const float* ln1_b   = (const float*)d_in[10];
    const float* ln2_g   = (const float*)d_in[11];
    const float* ln2_b   = (const float*)d_in[12];
    const float* qkv_w   = (const float*)d_in[13];
    const float* proj_w  = (const float*)d_in[14];
    const float* proj_b  = (const float*)d_in[15];
    const float* fc1_w   = (const float*)d_in[16];
    const float* fc1_b   = (const float*)d_in[17];
    const float* fc2_w   = (const float*)d_in[18];
    const float* fc2_b   = (const float*)d_in[19];
    const float* ad_dw   = (const float*)d_in[20];
    const float* ad_db   = (const float*)d_in[21];
    const float* ad_uw   = (const float*)d_in[22];
    const float* ad_ub   = (const float*)d_in[23];
    const float* ad1_dw  = (const float*)d_in[24];
    const float* ad1_db  = (const float*)d_in[25];
    const float* ad1_uw  = (const float*)d_in[26];
    const float* ad1_ub  = (const float*)d_in[27];
    const float* prompt  = (const float*)d_in[28];
    const float* bn_g    = (const float*)d_in[29];
    const float* bn_b    = (const float*)d_in[30];
    const float* bn_mean = (const float*)d_in[31];
    const float* bn_var  = (const float*)d_in[32];
    const float* qkv1_w  = (const float*)d_in[33];
    const float* proj1_w = (const float*)d_in[34];
    const float* proj1_b = (const float*)d_in[35];
    const float* ln3_g   = (const float*)d_in[36];
    const float* ln3_b   = (const float*)d_in[37];

    char* wsb = (char*)d_ws;
    float* XC   = (float*)(wsb + XC_OFF);
    float* VIS  = (float*)(wsb + VIS_OFF);
    bf16*  XNB  = (bf16*)(wsb + XNB_OFF);
    float* XFN  = (float*)(wsb + XFN_OFF);
    bf16*  BIG1 = (bf16*)(wsb + BIG1_OFF);
    bf16*  BIG2 = (bf16*)(wsb + BIG2_OFF);
    bf16*  ATT  = (bf16*)(wsb + ATT_OFF);
    bf16*  WB   = (bf16*)(wsb + WB_OFF);

    float* out_x    = (float*)d_out;
    float* out_attn = out_x + OUT_X;

    // --- weights -> bf16 (graph-safe: every call) ---
    k_wconv<<<(WB_TOTAL / 4 + 255) / 256, 256, 0, stream>>>(qkv_w, proj_w, fc1_w, fc2_w, qkv1_w, proj1_w, WB);

    // --- stage 1 ---
    k_build_ln<<<M1, 128, 0, stream>>>(x_in, prompt, ln1_g, ln1_b, XC, XNB);
    mf_gemm<<<dim3(18, 139), 256, 0, stream>>>(XNB, WB + WB_QKV, (const float*)nullptr, (const float*)nullptr, BIG1, M1, 1152, 384, 0);
    k_attn1<<<BB * HH, 256, 0, stream>>>(BIG1, XNB, out_attn);
    mf_gemm<<<dim3(6, 139), 256, 0, stream>>>(XNB, WB + WB_PROJ, proj_b, XC, XC, M1, 384, 384, 0);
    k_layernorm<<<M1, 128, 0, stream>>>(XC, XNB, ln2_g, ln2_b, 0);
    mf_gemm<<<dim3(24, 139), 256, 0, stream>>>(XNB, WB + WB_FC1, fc1_b, (const float*)nullptr, BIG2, M1, 1536, 384, 1);
    mf_gemm<<<dim3(6, 139), 256, 0, stream>>>(BIG2, WB + WB_FC2, fc2_b, (const float*)nullptr, XFN, M1, 384, 1536, 0);
    k_adapter<<<M1 / 4, 256, 0, stream>>>(XFN, XC, ad_dw, ad_db, ad_uw, ad_ub, XC, 0);

    // --- stage 2 (group attention on 8832 unique rows) ---
    k_layernorm<<<MG, 128, 0, stream>>>(XC, XNB, ln3_g, ln3_b, 1);
    mf_gemm<<<dim3(18, 138), 256, 0, stream>>>(XNB, WB + WB_QKV1, (const float*)nullptr, (const float*)nullptr, BIG1, MG, 1152, 384, 0);
    k_attn2<<<NGRP, 64, 0, stream>>>(BIG1, idx, BIG2);
    mf_gemm<<<dim3(6, 512), 256, 0, stream>>>(BIG2, WB + WB_PROJ1, proj1_b, (const float*)nullptr, ATT, NGRP * 16, 384, 384, 0);
    k_groupmax<<<NGRP, 128, 0, stream>>>(ATT, XC, idx, cidx, bn_g, bn_b, bn_mean, bn_var, VIS);
    k_propagate<<<BB * 128, 128, 0, stream>>>(center1, center2, XC, VIS, XFN);

    // --- final adapter (reads xc/xp directly; x_final never materialized) ---
    k_adapter<<<BB * 129 / 4, 256, 0, stream>>>(XFN, XC, ad1_dw, ad1_db, ad1_uw, ad1_ub, out_x, 1);
}

// Round 7
// 444.222 us; speedup vs baseline: 1.7778x; 1.0967x over previous
//
#include <hip/hip_runtime.h>
#include <hip/hip_bf16.h>

typedef __hip_bfloat16 bf16;
typedef __attribute__((ext_vector_type(8))) short short8;
typedef __attribute__((ext_vector_type(4))) float f32x4;

#define DEV static __device__ __forceinline__

DEV float b2f(bf16 v) { return __bfloat162float(v); }
DEV bf16 f2b(float v) { return __float2bfloat16(v); }
DEV unsigned short f2bu(float v) { return __builtin_bit_cast(unsigned short, __float2bfloat16(v)); }
DEV float u2f(unsigned short u) { return __uint_as_float(((unsigned int)u) << 16); }
DEV float gelu(float x) { return 0.5f * x * (1.0f + erff(x * 0.70710678118654752f)); }

// Problem constants
#define BB 64
#define NT 139     // 1 + T + G1
#define DD 384
#define TT 10
#define HH 6
#define GG 138     // G1 + T
#define M1 8896    // BB*NT = 64*139, multiple of 64
#define MG 8832    // BB*GG = 64*138, multiple of 64
#define NGRP 2048  // BB*S
#define SCALE 0.125f

// Workspace byte offsets (proven layout; + bf16 weights block = 90.4 MB)
#define XC_OFF   0UL          // f32 8896x384 residual stream, live whole call
#define VIS_OFF  13664256UL   // f32 2048x384
#define XNB_OFF  16809984UL   // bf16 8896x384: LN out; attn1 o; dead after consumer
#define XFN_OFF  23642112UL   // f32 8896x384: fc2 out; x_prop
#define BIG1_OFF 37875712UL   // bf16 8896x1152: qkv / qkv1
#define BIG2_OFF 58372096UL   // bf16 8896x1536 fc1h / bf16 32768x384 o1
#define ATT_OFF  XNB_OFF      // bf16 32768x384 proj1 out (overlays dead XNB..BIG1 prefix)
#define WB_OFF   85700608UL   // bf16 2359296: pre-converted weights

// bf16 weight block element offsets
#define WB_QKV   0
#define WB_PROJ  442368
#define WB_FC1   589824
#define WB_FC2   1179648
#define WB_QKV1  1769472
#define WB_PROJ1 2211840
#define WB_TOTAL 2359296

#define OUT_X 3170304  // 64*129*384

DEV float4 ld4(const float* p) { return *(const float4*)p; }
DEV float4 ld4(const bf16* p) {
    ushort4 u = *(const ushort4*)p;
    return make_float4(u2f(u.x), u2f(u.y), u2f(u.z), u2f(u.w));
}
DEV void stc(float* p, float v) { *p = v; }
DEV void stc(bf16* p, float v) { *p = f2b(v); }

// ---------- weights f32 -> bf16 (once per call) ----------
__global__ __launch_bounds__(256) void k_wconv(const float* __restrict__ w0, const float* __restrict__ w1,
                                               const float* __restrict__ w2, const float* __restrict__ w3,
                                               const float* __restrict__ w4, const float* __restrict__ w5,
                                               bf16* __restrict__ dst) {
    int i4 = (blockIdx.x * 256 + threadIdx.x) * 4;
    if (i4 >= WB_TOTAL) return;
    const float* s; int off;
    if (i4 < WB_PROJ)       { s = w0; off = WB_QKV; }
    else if (i4 < WB_FC1)   { s = w1; off = WB_PROJ; }
    else if (i4 < WB_FC2)   { s = w2; off = WB_FC1; }
    else if (i4 < WB_QKV1)  { s = w3; off = WB_FC2; }
    else if (i4 < WB_PROJ1) { s = w4; off = WB_QKV1; }
    else                    { s = w5; off = WB_PROJ1; }
    float4 v = *(const float4*)(s + (i4 - off));
    ushort4 u;
    u.x = f2bu(v.x); u.y = f2bu(v.y); u.z = f2bu(v.z); u.w = f2bu(v.w);
    *(ushort4*)((unsigned short*)dst + i4) = u;
}

// ---------- fused concat + LN1: xc row built AND layernormed -> xnb (one pass) ----------
__global__ __launch_bounds__(128) void k_build_ln(const float* __restrict__ x, const float* __restrict__ pe,
                                                  const float* __restrict__ g, const float* __restrict__ bta,
                                                  float* __restrict__ xc, bf16* __restrict__ dst) {
    int r = blockIdx.x;
    int n = r % NT, b = r / NT;
    const float* p;
    if (n == 0)       p = x + (size_t)(b * 129) * DD;
    else if (n <= TT) p = pe + (size_t)(n - 1) * DD;
    else              p = x + (size_t)(b * 129 + n - TT) * DD;
    int t = threadIdx.x;
    float v0 = p[t], v1 = p[t + 128], v2 = p[t + 256];
    float* xr = xc + (size_t)r * DD;
    xr[t] = v0; xr[t + 128] = v1; xr[t + 256] = v2;
    __shared__ float red[4];
    float s = v0 + v1 + v2;
    for (int off = 32; off; off >>= 1) s += __shfl_down(s, off, 64);
    if ((t & 63) == 0) red[t >> 6] = s;
    __syncthreads();
    float mean = (red[0] + red[1]) * (1.0f / 384.0f);
    float d0 = v0 - mean, d1 = v1 - mean, d2 = v2 - mean;
    float s2 = d0 * d0 + d1 * d1 + d2 * d2;
    for (int off = 32; off; off >>= 1) s2 += __shfl_down(s2, off, 64);
    if ((t & 63) == 0) red[2 + (t >> 6)] = s2;
    __syncthreads();
    float rstd = rsqrtf((red[2] + red[3]) * (1.0f / 384.0f) + 1e-5f);
    bf16* q = dst + (size_t)r * DD;
    q[t]       = f2b(d0 * rstd * g[t]       + bta[t]);
    q[t + 128] = f2b(d1 * rstd * g[t + 128] + bta[t + 128]);
    q[t + 256] = f2b(d2 * rstd * g[t + 256] + bta[t + 256]);
}

// ---------- layernorm f32 -> bf16 (mode 1: gather row (r/138)*139+1+(r%138)) ----------
__global__ __launch_bounds__(128) void k_layernorm(const float* __restrict__ src, bf16* __restrict__ dst,
                                                   const float* __restrict__ g, const float* __restrict__ bta,
                                                   int mode) {
    int r = blockIdx.x;
    int srow = r;
    if (mode) srow = (r / GG) * NT + 1 + (r % GG);
    const float* p = src + (size_t)srow * DD;
    int t = threadIdx.x;
    float v0 = p[t], v1 = p[t + 128], v2 = p[t + 256];
    __shared__ float red[4];
    float s = v0 + v1 + v2;
    for (int off = 32; off; off >>= 1) s += __shfl_down(s, off, 64);
    if ((t & 63) == 0) red[t >> 6] = s;
    __syncthreads();
    float mean = (red[0] + red[1]) * (1.0f / 384.0f);
    float d0 = v0 - mean, d1 = v1 - mean, d2 = v2 - mean;
    float s2 = d0 * d0 + d1 * d1 + d2 * d2;
    for (int off = 32; off; off >>= 1) s2 += __shfl_down(s2, off, 64);
    if ((t & 63) == 0) red[2 + (t >> 6)] = s2;
    __syncthreads();
    float rstd = rsqrtf((red[2] + red[3]) * (1.0f / 384.0f) + 1e-5f);
    bf16* q = dst + (size_t)r * DD;
    q[t]       = f2b(d0 * rstd * g[t]       + bta[t]);
    q[t + 128] = f2b(d1 * rstd * g[t + 128] + bta[t + 128]);
    q[t + 256] = f2b(d2 * rstd * g[t + 256] + bta[t + 256]);
}

// ---------- MFMA GEMM: C[M,N] = act(A[M,K]bf16 @ W[N,K]^T bf16 + bias) (+res) ----------
// BM=64 BN=64 BK=64, 4 waves (2x2) each 32x32 via 2x2x(2 ks) 16x16x32 MFMAs.
// 2-stage register prefetch: load tile k+1 to regs while computing tile k from LDS.
// Requires: M % 64 == 0 (true for all call sites), N % 64 == 0, K % 64 == 0.
template <typename TC>
__global__ __launch_bounds__(256) void mf_gemm(const bf16* __restrict__ A, const bf16* __restrict__ W,
                                               const float* __restrict__ bias, const float* __restrict__ res,
                                               TC* __restrict__ C, int M, int N, int K, int act) {
    __shared__ bf16 As[64][72];
    __shared__ bf16 Ws[64][72];
    int t = threadIdx.x;
    int m0 = blockIdx.y * 64, n0 = blockIdx.x * 64;
    int lane = t & 63, wv = t >> 6;
    int wm = (wv >> 1) * 32, wn = (wv & 1) * 32;
    int fr = lane & 15, fq = lane >> 4;
    int sr = t >> 2, sc = (t & 3) * 16;   // staging: 4 thr/row, 32B (2 x uint4) each
    const bf16* pa = A + (size_t)(m0 + sr) * K + sc;
    const bf16* pw = W + (size_t)(n0 + sr) * K + sc;
    uint4 ra0 = *(const uint4*)pa;
    uint4 ra1 = *(const uint4*)(pa + 8);
    uint4 rw0 = *(const uint4*)pw;
    uint4 rw1 = *(const uint4*)(pw + 8);
    f32x4 acc[2][2] = {};
    int k0 = 0;
    for (;;) {
        *(uint4*)&As[sr][sc] = ra0; *(uint4*)&As[sr][sc + 8] = ra1;
        *(uint4*)&Ws[sr][sc] = rw0; *(uint4*)&Ws[sr][sc + 8] = rw1;
        __syncthreads();
        k0 += 64;
        bool more = (k0 < K);
        if (more) {
            ra0 = *(const uint4*)(pa + k0); ra1 = *(const uint4*)(pa + k0 + 8);
            rw0 = *(const uint4*)(pw + k0); rw1 = *(const uint4*)(pw + k0 + 8);
        }
#pragma unroll
        for (int ks = 0; ks < 2; ++ks) {
            short8 a0 = *(const short8*)&As[wm + fr][ks * 32 + fq * 8];
            short8 a1 = *(const short8*)&As[wm + 16 + fr][ks * 32 + fq * 8];
            short8 b0 = *(const short8*)&Ws[wn + fr][ks * 32 + fq * 8];
            short8 b1 = *(const short8*)&Ws[wn + 16 + fr][ks * 32 + fq * 8];
            acc[0][0] = __builtin_amdgcn_mfma_f32_16x16x32_bf16(a0, b0, acc[0][0], 0, 0, 0);
            acc[0][1] = __builtin_amdgcn_mfma_f32_16x16x32_bf16(a0, b1, acc[0][1], 0, 0, 0);
            acc[1][0] = __builtin_amdgcn_mfma_f32_16x16x32_bf16(a1, b0, acc[1][0], 0, 0, 0);
            acc[1][1] = __builtin_amdgcn_mfma_f32_16x16x32_bf16(a1, b1, acc[1][1], 0, 0, 0);
        }
        if (!more) break;
        __syncthreads();
    }
#pragma unroll
    for (int i = 0; i < 2; ++i) {
#pragma unroll
        for (int r = 0; r < 4; ++r) {
            int row = m0 + wm + i * 16 + fq * 4 + r;
            size_t ro = (size_t)row * N;
#pragma unroll
            for (int j = 0; j < 2; ++j) {
                int col = n0 + wn + j * 16 + fr;
                float c = acc[i][j][r];
                if (bias) c += bias[col];
                if (act == 1) c = gelu(c);
                if (res) c += res[ro + col];
                stc(&C[ro + col], c);
            }
        }
    }
}

// ---------- fused N=16 adapter: weights in LDS (transposed, bank-tuned); 8 rows/block ----------
// Bottleneck fix: per-lane strided weight reads (64 cache lines / wave-load) replaced by
// LDS-resident DWT[j][g] (stride 17) + UWT[c][d] (stride 388); both read conflict-free(<=2-way).
// mode 0: dst[row] += 0.7*(gelu(row@dw^T+db)@uw^T+ub) + row       rows = M1, row src = xfn
// mode 1: row->(b,no); src = no==0 ? xc[b*NT] : xp[b*128+no-1];
//         dst[row] = gelu(src@dw^T+db)@uw^T+ub + src               rows = BB*129
DEV const float* adapter_src(const float* xfn, const float* xc, int row, int mode) {
    if (mode == 0) return xfn + (size_t)row * DD;
    int b = row / 129, no = row % 129;
    return (no == 0) ? xc + (size_t)(b * NT) * DD
                     : xfn + (size_t)(b * 128 + no - 1) * DD;
}
__global__ __launch_bounds__(512) void k_adapter(const float* __restrict__ xfn, const float* __restrict__ xc,
                                                 const float* __restrict__ dw, const float* __restrict__ db,
                                                 const float* __restrict__ uw, const float* __restrict__ ub,
                                                 float* __restrict__ dst, int mode) {
    __shared__ float DWT[384 * 17];   // DWT[j*17+g] = dw[g][j]
    __shared__ float UWT[16 * 388];   // UWT[c*388+d] = uw[d][c]
    int t = threadIdx.x, lane = t & 63, wv = t >> 6;
    // stage dw (6144 floats): 3 coalesced float4 loads/thread, transposed scatter to LDS
#pragma unroll
    for (int i = 0; i < 3; ++i) {
        int f = (t + i * 512) * 4;
        int g = f / DD, j = f % DD;
        float4 v = *(const float4*)(dw + f);
        DWT[(j + 0) * 17 + g] = v.x; DWT[(j + 1) * 17 + g] = v.y;
        DWT[(j + 2) * 17 + g] = v.z; DWT[(j + 3) * 17 + g] = v.w;
    }
    // stage uw (6144 floats): transposed scatter
#pragma unroll
    for (int i = 0; i < 3; ++i) {
        int f = (t + i * 512) * 4;
        int d = f / 16, c = f % 16;
        float4 v = *(const float4*)(uw + f);
        UWT[(c + 0) * 388 + d] = v.x; UWT[(c + 1) * 388 + d] = v.y;
        UWT[(c + 2) * 388 + d] = v.z; UWT[(c + 3) * 388 + d] = v.w;
    }
    __syncthreads();
    int row = blockIdx.x * 8 + wv;
    const float* s = adapter_src(xfn, xc, row, mode);   // wave-uniform
    float* d = dst + (size_t)row * DD;
    // down: lane = (g 0..15, seg 0..3); row read from global is a 16-lane broadcast per seg;
    // seg-rotated j order makes the 4 segs hit disjoint bank groups (2-way max).
    int g = lane & 15, seg = lane >> 4;
    const float* sg = s + seg * 96;
    float part = 0.f;
#pragma unroll
    for (int j = 0; j < 24; ++j) {
        int jj = j + seg * 6; if (jj >= 24) jj -= 24;
        float4 a = *(const float4*)(sg + jj * 4);
        int jb = seg * 96 + jj * 4;
        part += a.x * DWT[(jb + 0) * 17 + g] + a.y * DWT[(jb + 1) * 17 + g]
              + a.z * DWT[(jb + 2) * 17 + g] + a.w * DWT[(jb + 3) * 17 + g];
    }
    part += __shfl_xor(part, 16, 64);
    part += __shfl_xor(part, 32, 64);
    float tg = gelu(part + db[g]);   // every lane holds full dot for its g = lane&15
    float tl[16];
#pragma unroll
    for (int c = 0; c < 16; ++c) tl[c] = __shfl(tg, c, 64);
    // up: 6 outputs/lane; UWT reads are lane-consecutive (conflict-free)
#pragma unroll
    for (int k = 0; k < 6; ++k) {
        int dd = lane + k * 64;
        float acc = ub[dd];
#pragma unroll
        for (int c = 0; c < 16; ++c) acc += tl[c] * UWT[c * 388 + dd];
        if (mode == 0) d[dd] += 0.7f * acc + s[dd];
        else           d[dd] = acc + s[dd];
    }
}

// ---------- stage-1 attention (MFMA): one block per (b,h) ----------
__global__ __launch_bounds__(256) void k_attn1(const bf16* __restrict__ qkv, bf16* __restrict__ o_out,
                                               float* __restrict__ attn_out) {
    int bh = blockIdx.x;
    int b = bh / HH, h = bh % HH;
    __shared__ unsigned short Kl[144][72];
    __shared__ unsigned short Vt[64][160];
    __shared__ unsigned short Pl[4][16][160];
    int t = threadIdx.x;
    int lane = t & 63, wv = t >> 6;
    int fr = lane & 15, fq = lane >> 4;
    const unsigned short* q16 = (const unsigned short*)qkv;
    size_t base = (size_t)b * NT * 1152;

    uint4 z4 = make_uint4(0, 0, 0, 0);
    for (int i = t * 8; i < 64 * 160; i += 2048) *(uint4*)(&Vt[0][0] + i) = z4;
    for (int i = t * 8; i < 4 * 16 * 160; i += 2048) *(uint4*)(&Pl[0][0][0] + i) = z4;
    for (int i = t; i < 144 * 8; i += 256) {
        int row = i >> 3, ch = (i & 7) * 8;
        uint4 v = z4;
        if (row < NT) v = *(const uint4*)(q16 + base + row * 1152 + 384 + h * 64 + ch);
        *(uint4*)&Kl[row][ch] = v;
    }
    for (int i = t; i < NT * 16; i += 256) {
        int m = i >> 4, dq = (i & 15) * 4;
        ushort4 v = *(const ushort4*)(q16 + base + m * 1152 + 768 + h * 64 + dq);
        Vt[dq + 0][m] = v.x; Vt[dq + 1][m] = v.y;
        Vt[dq + 2][m] = v.z; Vt[dq + 3][m] = v.w;
    }
    __syncthreads();

    for (int nt = wv; nt < 9; nt += 4) {
        int n0 = nt * 16;
        int arow = n0 + fr; if (arow > NT - 1) arow = NT - 1;
        const unsigned short* qp = q16 + base + (size_t)arow * 1152 + h * 64 + fq * 8;
        short8 a0 = *(const short8*)qp;
        short8 a1 = *(const short8*)(qp + 32);
        f32x4 s[9] = {};
#pragma unroll
        for (int mt = 0; mt < 9; ++mt) {
            short8 b0 = *(const short8*)&Kl[mt * 16 + fr][fq * 8];
            short8 b1 = *(const short8*)&Kl[mt * 16 + fr][32 + fq * 8];
            s[mt] = __builtin_amdgcn_mfma_f32_16x16x32_bf16(a0, b0, s[mt], 0, 0, 0);
            s[mt] = __builtin_amdgcn_mfma_f32_16x16x32_bf16(a1, b1, s[mt], 0, 0, 0);
        }
#pragma unroll
        for (int r = 0; r < 4; ++r) {
            float e[9];
            float mx = -1e30f;
#pragma unroll
            for (int mt = 0; mt < 9; ++mt) {
                int col = mt * 16 + fr;
                float v = (col < NT) ? s[mt][r] * SCALE : -1e30f;
                e[mt] = v;
                mx = fmaxf(mx, v);
            }
#pragma unroll
            for (int off = 1; off < 16; off <<= 1) mx = fmaxf(mx, __shfl_xor(mx, off, 64));
            float sm = 0.f;
#pragma unroll
            for (int mt = 0; mt < 9; ++mt) { e[mt] = __expf(e[mt] - mx); sm += e[mt]; }
#pragma unroll
            for (int off = 1; off < 16; off <<= 1) sm += __shfl_xor(sm, off, 64);
            float inv = 1.0f / sm;
            int n = n0 + fq * 4 + r;
            bool nv = n < NT;
            size_t ab = ((size_t)(b * HH + h) * NT + n) * NT;
#pragma unroll
            for (int mt = 0; mt < 9; ++mt) {
                float p = e[mt] * inv;
                int col = mt * 16 + fr;
                if (nv && col < NT) attn_out[ab + col] = p;
                Pl[wv][fq * 4 + r][col] = f2bu(p);
            }
        }
        __syncthreads();
        f32x4 oac[4] = {};
#pragma unroll
        for (int ks = 0; ks < 5; ++ks) {
            short8 ap = *(const short8*)&Pl[wv][fr][ks * 32 + fq * 8];
#pragma unroll
            for (int dt = 0; dt < 4; ++dt) {
                short8 bv = *(const short8*)&Vt[dt * 16 + fr][ks * 32 + fq * 8];
                oac[dt] = __builtin_amdgcn_mfma_f32_16x16x32_bf16(ap, bv, oac[dt], 0, 0, 0);
            }
        }
#pragma unroll
        for (int dt = 0; dt < 4; ++dt)
#pragma unroll
            for (int r = 0; r < 4; ++r) {
                int n = n0 + fq * 4 + r;
                if (n < NT)
                    o_out[((size_t)(b * NT + n)) * DD + h * 64 + dt * 16 + fr] = f2b(oac[dt][r]);
            }
    }
}

// ---------- stage-2 per-group attention (MFMA): one wave per group ----------
__global__ __launch_bounds__(64) void k_attn2(const bf16* __restrict__ qkv, const int* __restrict__ idx,
                                              bf16* __restrict__ o1) {
    int g = blockIdx.x;
    __shared__ unsigned short Vt2[64][40];
    __shared__ unsigned short P2[16][40];
    __shared__ int ridx[16];
    int t = threadIdx.x;
    int fr = t & 15, fq = t >> 4;
    const unsigned short* q16 = (const unsigned short*)qkv;
    if (t < 16) ridx[t] = idx[g * 16 + t];
    uint4 z4 = make_uint4(0, 0, 0, 0);
    for (int i = t * 8; i < 64 * 40; i += 512) *(uint4*)(&Vt2[0][0] + i) = z4;
    for (int i = t * 8; i < 16 * 40; i += 512) *(uint4*)(&P2[0][0] + i) = z4;
    __syncthreads();
    size_t qb = (size_t)ridx[fr] * 1152;
    for (int h = 0; h < HH; ++h) {
        for (int i = t; i < 256; i += 64) {
            int m = i >> 4, dq = (i & 15) * 4;
            ushort4 v = *(const ushort4*)(q16 + (size_t)ridx[m] * 1152 + 768 + h * 64 + dq);
            Vt2[dq + 0][m] = v.x; Vt2[dq + 1][m] = v.y;
            Vt2[dq + 2][m] = v.z; Vt2[dq + 3][m] = v.w;
        }
        __syncthreads();
        const unsigned short* qp = q16 + qb + h * 64 + fq * 8;
        const unsigned short* kp = q16 + qb + 384 + h * 64 + fq * 8;
        short8 a0 = *(const short8*)qp;
        short8 a1 = *(const short8*)(qp + 32);
        short8 b0 = *(const short8*)kp;
        short8 b1 = *(const short8*)(kp + 32);
        f32x4 s = {};
        s = __builtin_amdgcn_mfma_f32_16x16x32_bf16(a0, b0, s, 0, 0, 0);
        s = __builtin_amdgcn_mfma_f32_16x16x32_bf16(a1, b1, s, 0, 0, 0);
#pragma unroll
        for (int r = 0; r < 4; ++r) {
            float v = s[r] * SCALE;
            float mx = v;
#pragma unroll
            for (int off = 1; off < 16; off <<= 1) mx = fmaxf(mx, __shfl_xor(mx, off, 64));
            float e = __expf(v - mx), sm = e;
#pragma unroll
            for (int off = 1; off < 16; off <<= 1) sm += __shfl_xor(sm, off, 64);
            P2[fq * 4 + r][fr] = f2bu(e / sm);
        }
        __syncthreads();
        short8 ap = *(const short8*)&P2[fr][fq * 8];
        f32x4 oac[4] = {};
#pragma unroll
        for (int dt = 0; dt < 4; ++dt) {
            short8 bv = *(const short8*)&Vt2[dt * 16 + fr][fq * 8];
            oac[dt] = __builtin_amdgcn_mfma_f32_16x16x32_bf16(ap, bv, oac[dt], 0, 0, 0);
        }
#pragma unroll
        for (int dt = 0; dt < 4; ++dt)
#pragma unroll
            for (int r = 0; r < 4; ++r)
                o1[((size_t)(g * 16 + fq * 4 + r)) * DD + h * 64 + dt * 16 + fr] = f2b(oac[dt][r]);
        __syncthreads();
    }
}

// ---------- group residual + max + BN + GELU + centers -> vis ----------
__global__ __launch_bounds__(128) void k_groupmax(const bf16* __restrict__ att, const float* __restrict__ xc,
                                                  const int* __restrict__ idx, const int* __restrict__ cidx,
                                                  const float* __restrict__ bg, const float* __restrict__ bb,
                                                  const float* __restrict__ bmean, const float* __restrict__ bvar,
                                                  float* __restrict__ vis) {
    int g = blockIdx.x, t = threadIdx.x;
    __shared__ int rows[16];
    __shared__ int crow;
    if (t < 16) { int r = idx[g * 16 + t]; rows[t] = (r / GG) * NT + 1 + (r % GG); }
    if (t == 16) { int r = cidx[g]; crow = (r / GG) * NT + 1 + (r % GG); }
    __syncthreads();
    for (int d = t; d < DD; d += 128) {
        float m = -INFINITY;
#pragma unroll
        for (int j = 0; j < 16; ++j) {
            float v = b2f(att[((size_t)(g * 16 + j)) * DD + d]) + xc[(size_t)rows[j] * DD + d];
            m = fmaxf(m, v);
        }
        float bn = (m - bmean[d]) * rsqrtf(bvar[d] + 1e-5f) * bg[d] + bb[d];
        bn = gelu(bn);
        vis[(size_t)g * DD + d] = bn + 0.3f * xc[(size_t)crow * DD + d];
    }
}

// ---------- propagate ----------
__global__ __launch_bounds__(128) void k_propagate(const float* __restrict__ c1, const float* __restrict__ c2,
                                                   const float* __restrict__ xc, const float* __restrict__ vis,
                                                   float* __restrict__ xp) {
    int blk = blockIdx.x;
    int b = blk >> 7, i = blk & 127;
    int t = threadIdx.x;
    __shared__ float wl[32];
    __shared__ float wsum;
    if (t < 32) {
        float dx = c1[(b * 128 + i) * 3 + 0] - c2[(b * 32 + t) * 3 + 0];
        float dy = c1[(b * 128 + i) * 3 + 1] - c2[(b * 32 + t) * 3 + 1];
        float dz = c1[(b * 128 + i) * 3 + 2] - c2[(b * 32 + t) * 3 + 2];
        wl[t] = 1.0f / (dx * dx + dy * dy + dz * dz + 1e-8f);
    }
    __syncthreads();
    if (t == 0) {
        float s = 0.f;
        for (int j = 0; j < 32; ++j) s += wl[j];
        wsum = s;
    }
    __syncthreads();
    float sc = 0.3f / wsum;
    for (int d = t; d < DD; d += 128) {
        float acc = 0.f;
#pragma unroll 8
        for (int j = 0; j < 32; ++j) acc += wl[j] * vis[((size_t)(b * 32 + j)) * DD + d];
        xp[((size_t)(b * 128 + i)) * DD + d] = xc[((size_t)(b * NT + 11 + i)) * DD + d] + sc * acc;
    }
}

extern "C" void kernel_launch(void* const* d_in, const int* in_sizes, int n_in,
                              void* d_out, int out_size, void* d_ws, size_t ws_size,
                              hipStream_t stream) {
    const float* x_in    = (const float*)d_in[0];
    const float* center1 = (const float*)d_in[2];
    const float* center2 = (const float*)d_in[3];
    const int*   idx     = (const int*)d_in[5];
    const int*   cidx    = (const int*)d_in[6];
    const float* ln1_g   = (const float*)d_in[9];
    const float* ln1_b   = (const float*)d_in[10];
    const float* ln2_g   = (const float*)d_in[11];
    const float* ln2_b   = (const float*)d_in[12];
    const float* qkv_w   = (const float*)d_in[13];
    const float* proj_w  = (const float*)d_in[14];
    const float* proj_b  = (const float*)d_in[15];
    const float* fc1_w   = (const float*)d_in[16];
    const float* fc1_b   = (const float*)d_in[17];
    const float* fc2_w   = (const float*)d_in[18];
    const float* fc2_b   = (const float*)d_in[19];
    const float* ad_dw   = (const float*)d_in[20];
    const float* ad_db   = (const float*)d_in[21];
    const float* ad_uw   = (const float*)d_in[22];
    const float* ad_ub   = (const float*)d_in[23];
    const float* ad1_dw  = (const float*)d_in[24];
    const float* ad1_db  = (const float*)d_in[25];
    const float* ad1_uw  = (const float*)d_in[26];
    const float* ad1_ub  = (const float*)d_in[27];
    const float* prompt  = (const float*)d_in[28];
    const float* bn_g    = (const float*)d_in[29];
    const float* bn_b    = (const float*)d_in[30];
    const float* bn_mean = (const float*)d_in[31];
    const float* bn_var  = (const float*)d_in[32];
    const float* qkv1_w  = (const float*)d_in[33];
    const float* proj1_w = (const float*)d_in[34];
    const float* proj1_b = (const float*)d_in[35];
    const float* ln3_g   = (const float*)d_in[36];
    const float* ln3_b   = (const float*)d_in[37];

    char* wsb = (char*)d_ws;
    float* XC   = (float*)(wsb + XC_OFF);
    float* VIS  = (float*)(wsb + VIS_OFF);
    bf16*  XNB  = (bf16*)(wsb + XNB_OFF);
    float* XFN  = (float*)(wsb + XFN_OFF);
    bf16*  BIG1 = (bf16*)(wsb + BIG1_OFF);
    bf16*  BIG2 = (bf16*)(wsb + BIG2_OFF);
    bf16*  ATT  = (bf16*)(wsb + ATT_OFF);
    bf16*  WB   = (bf16*)(wsb + WB_OFF);

    float* out_x    = (float*)d_out;
    float* out_attn = out_x + OUT_X;

    // --- weights -> bf16 (graph-safe: every call) ---
    k_wconv<<<(WB_TOTAL / 4 + 255) / 256, 256, 0, stream>>>(qkv_w, proj_w, fc1_w, fc2_w, qkv1_w, proj1_w, WB);

    // --- stage 1 ---
    k_build_ln<<<M1, 128, 0, stream>>>(x_in, prompt, ln1_g, ln1_b, XC, XNB);
    mf_gemm<<<dim3(18, 139), 256, 0, stream>>>(XNB, WB + WB_QKV, (const float*)nullptr, (const float*)nullptr, BIG1, M1, 1152, 384, 0);
    k_attn1<<<BB * HH, 256, 0, stream>>>(BIG1, XNB, out_attn);
    mf_gemm<<<dim3(6, 139), 256, 0, stream>>>(XNB, WB + WB_PROJ, proj_b, XC, XC, M1, 384, 384, 0);
    k_layernorm<<<M1, 128, 0, stream>>>(XC, XNB, ln2_g, ln2_b, 0);
    mf_gemm<<<dim3(24, 139), 256, 0, stream>>>(XNB, WB + WB_FC1, fc1_b, (const float*)nullptr, BIG2, M1, 1536, 384, 1);
    mf_gemm<<<dim3(6, 139), 256, 0, stream>>>(BIG2, WB + WB_FC2, fc2_b, (const float*)nullptr, XFN, M1, 384, 1536, 0);
    k_adapter<<<M1 / 8, 512, 0, stream>>>(XFN, XC, ad_dw, ad_db, ad_uw, ad_ub, XC, 0);

    // --- stage 2 (group attention on 8832 unique rows) ---
    k_layernorm<<<MG, 128, 0, stream>>>(XC, XNB, ln3_g, ln3_b, 1);
    mf_gemm<<<dim3(18, 138), 256, 0, stream>>>(XNB, WB + WB_QKV1, (const float*)nullptr, (const float*)nullptr, BIG1, MG, 1152, 384, 0);
    k_attn2<<<NGRP, 64, 0, stream>>>(BIG1, idx, BIG2);
    mf_gemm<<<dim3(6, 512), 256, 0, stream>>>(BIG2, WB + WB_PROJ1, proj1_b, (const float*)nullptr, ATT, NGRP * 16, 384, 384, 0);
    k_groupmax<<<NGRP, 128, 0, stream>>>(ATT, XC, idx, cidx, bn_g, bn_b, bn_mean, bn_var, VIS);
    k_propagate<<<BB * 128, 128, 0, stream>>>(center1, center2, XC, VIS, XFN);

    // --- final adapter (reads xc/xp directly; x_final never materialized) ---
    k_adapter<<<BB * 129 / 8, 512, 0, stream>>>(XFN, XC, ad1_dw, ad1_db, ad1_uw, ad1_ub, out_x, 1);
}